// Round 1
// baseline (2674.326 us; speedup 1.0000x reference)
//
#include <hip/hip_runtime.h>
#include <math.h>

#define DEV __device__ __forceinline__

DEV float sigm(float x) { return 1.0f / (1.0f + expf(-x)); }
DEV float lrelu02(float x) { return x > 0.0f ? x : 0.2f * x; }
DEV float readl(float v, int l) {
    return __int_as_float(__builtin_amdgcn_readlane(__float_as_int(v), l));
}

// ---------------------------------------------------------------------------
// LSTM: 2 layers, H=64, sequential over T. One block of 512 threads.
// Threads [0,256): layer-0 gates (W_hh0 row in regs). Threads [256,512):
// layer-1 gates (W_hh1 + W_ih1 rows in regs; W_hh1 part computed early since
// it only needs h1(t-1)). Epilogue: tsb[c] = sum_k h1[k]*W1[16+k][c].
// ---------------------------------------------------------------------------
__global__ __launch_bounds__(512) void k_lstm(
    const float* __restrict__ ts,
    const float* __restrict__ Wih0, const float* __restrict__ Whh0, const float* __restrict__ b0,
    const float* __restrict__ Wih1, const float* __restrict__ Whh1, const float* __restrict__ b1,
    const float* __restrict__ W1, float* __restrict__ tsb, int T)
{
    __shared__ __align__(16) float h0s[64], c0s[64], h1s[64], c1s[64];
    __shared__ float g0[256], g1[256];
    int tid = threadIdx.x;

    float wA[64], wB[64], wih[3], bias;
    if (tid < 256) {
        bias = b0[tid];
#pragma unroll
        for (int k = 0; k < 3; k++) wih[k] = Wih0[tid * 3 + k];
#pragma unroll
        for (int k = 0; k < 64; k++) wA[k] = Whh0[tid * 64 + k];
#pragma unroll
        for (int k = 0; k < 64; k++) wB[k] = 0.0f;
    } else {
        int j = tid - 256;
        bias = b1[j];
        wih[0] = wih[1] = wih[2] = 0.0f;
#pragma unroll
        for (int k = 0; k < 64; k++) wA[k] = Whh1[j * 64 + k];
#pragma unroll
        for (int k = 0; k < 64; k++) wB[k] = Wih1[j * 64 + k];
    }
    if (tid < 64) { h0s[tid] = 0.f; c0s[tid] = 0.f; h1s[tid] = 0.f; c1s[tid] = 0.f; }
    __syncthreads();

    for (int t = 0; t < T; ++t) {
        if (tid < 256) {
            float acc = bias + ts[t*3+0]*wih[0] + ts[t*3+1]*wih[1] + ts[t*3+2]*wih[2];
#pragma unroll
            for (int k = 0; k < 64; k += 4) {
                float4 hv = *(const float4*)&h0s[k];
                acc += hv.x*wA[k] + hv.y*wA[k+1] + hv.z*wA[k+2] + hv.w*wA[k+3];
            }
            g0[tid] = acc;
        } else {
            int j = tid - 256;
            float acc = bias;
#pragma unroll
            for (int k = 0; k < 64; k += 4) {
                float4 hv = *(const float4*)&h1s[k];
                acc += hv.x*wA[k] + hv.y*wA[k+1] + hv.z*wA[k+2] + hv.w*wA[k+3];
            }
            g1[j] = acc;
        }
        __syncthreads();
        if (tid < 64) {
            float i = sigm(g0[tid]), f = sigm(g0[tid+64]);
            float gg = tanhf(g0[tid+128]), o = sigm(g0[tid+192]);
            float c = f * c0s[tid] + i * gg;
            c0s[tid] = c; h0s[tid] = o * tanhf(c);
        }
        __syncthreads();
        if (tid >= 256) {
            int j = tid - 256;
            float acc = g1[j];
#pragma unroll
            for (int k = 0; k < 64; k += 4) {
                float4 hv = *(const float4*)&h0s[k];
                acc += hv.x*wB[k] + hv.y*wB[k+1] + hv.z*wB[k+2] + hv.w*wB[k+3];
            }
            g1[j] = acc;
        }
        __syncthreads();
        if (tid < 64) {
            float i = sigm(g1[tid]), f = sigm(g1[tid+64]);
            float gg = tanhf(g1[tid+128]), o = sigm(g1[tid+192]);
            float c = f * c1s[tid] + i * gg;
            c1s[tid] = c; h1s[tid] = o * tanhf(c);
        }
        __syncthreads();
    }
    if (tid < 128) {
        float acc = 0.f;
#pragma unroll
        for (int k = 0; k < 64; k++) acc += h1s[k] * W1[(16 + k) * 128 + tid];
        tsb[tid] = acc;
    }
}

// ---------------------------------------------------------------------------
// GEMM: Y[n][c] = bias[c] + sum_k X[n][k]*W[k][c], C=128 fixed.
// Wave handles one column-half (64 cols) of a node; W column in registers;
// X row read through wave-uniform (scalar-cached) loads.
// ---------------------------------------------------------------------------
template <int K>
__global__ __launch_bounds__(256) void k_gemm(
    const float* __restrict__ X, const float* __restrict__ W,
    const float* __restrict__ bias, float* __restrict__ Y, int N)
{
    int tid = threadIdx.x;
    int lane = tid & 63;
    int gw = (blockIdx.x * blockDim.x + tid) >> 6;
    int half = gw & 1;
    int col = lane + 64 * half;
    float wreg[K];
#pragma unroll
    for (int k = 0; k < K; k++) wreg[k] = W[k * 128 + col];
    float b = bias ? bias[col] : 0.0f;
    int total_waves = (gridDim.x * blockDim.x) >> 6;
    int nstride = total_waves >> 1;
    for (int n = (gw >> 1); n < N; n += nstride) {
        int nu = __builtin_amdgcn_readfirstlane(n);
        const float* xrow = X + (size_t)nu * K;
        float acc = b;
#pragma unroll
        for (int k = 0; k < K; k++) acc += xrow[k] * wreg[k];
        Y[(size_t)nu * 128 + col] = acc;
    }
}

// ---------------------------------------------------------------------------
// Attention projections: a_src[n][h] = sum_c Wx[n][c]*A[c][h],
//                        a_dst[n][h] = sum_c Wx[n][c]*A[128+c][h].
// Wave per node; lane owns cols {lane, lane+64}; shuffle-reduce 8 dots.
// ---------------------------------------------------------------------------
__global__ __launch_bounds__(256) void k_att(
    const float* __restrict__ Wx, const float* __restrict__ A,
    float* __restrict__ asrc, float* __restrict__ adst, int N)
{
    int tid = threadIdx.x;
    int lane = tid & 63;
    int gw = (blockIdx.x * blockDim.x + tid) >> 6;
    int waves = (gridDim.x * blockDim.x) >> 6;
    float4 s0 = ((const float4*)A)[lane];
    float4 s1 = ((const float4*)A)[lane + 64];
    float4 d0 = ((const float4*)A)[lane + 128];
    float4 d1 = ((const float4*)A)[lane + 192];
    for (int n = gw; n < N; n += waves) {
        float w0 = Wx[(size_t)n * 128 + lane];
        float w1 = Wx[(size_t)n * 128 + 64 + lane];
        float as[4], ad[4];
        as[0] = w0*s0.x + w1*s1.x; as[1] = w0*s0.y + w1*s1.y;
        as[2] = w0*s0.z + w1*s1.z; as[3] = w0*s0.w + w1*s1.w;
        ad[0] = w0*d0.x + w1*d1.x; ad[1] = w0*d0.y + w1*d1.y;
        ad[2] = w0*d0.z + w1*d1.z; ad[3] = w0*d0.w + w1*d1.w;
#pragma unroll
        for (int off = 32; off; off >>= 1) {
#pragma unroll
            for (int h = 0; h < 4; h++) {
                as[h] += __shfl_xor(as[h], off, 64);
                ad[h] += __shfl_xor(ad[h], off, 64);
            }
        }
        if (lane == 0) {
            float4 o1; o1.x = as[0]; o1.y = as[1]; o1.z = as[2]; o1.w = as[3];
            float4 o2; o2.x = ad[0]; o2.y = ad[1]; o2.z = ad[2]; o2.w = ad[3];
            ((float4*)asrc)[n] = o1;
            ((float4*)adst)[n] = o2;
        }
    }
}

// ---------------------------------------------------------------------------
// Edge pass 1: denom[d][h] += exp(leaky_relu(a_src[s][h]+a_dst[d][h])).
// Global-max subtraction is skipped: it cancels except via the 1e-9 epsilons
// (relative error ~1e-8 given |e| <~ 1 here).
// ---------------------------------------------------------------------------
__global__ __launch_bounds__(256) void k_edge_denom(
    const int* __restrict__ ei, const float* __restrict__ asrc,
    const float* __restrict__ adst, float* __restrict__ denom, int E)
{
    int stride = gridDim.x * blockDim.x;
    for (int e = blockIdx.x * blockDim.x + threadIdx.x; e < E; e += stride) {
        int s = ei[e], d = ei[E + e];
        float4 as = ((const float4*)asrc)[s];
        float4 ad = ((const float4*)adst)[d];
        float e0 = expf(lrelu02(as.x + ad.x));
        float e1 = expf(lrelu02(as.y + ad.y));
        float e2 = expf(lrelu02(as.z + ad.z));
        float e3 = expf(lrelu02(as.w + ad.w));
        unsafeAtomicAdd(denom + (size_t)d * 4 + 0, e0);
        unsafeAtomicAdd(denom + (size_t)d * 4 + 1, e1);
        unsafeAtomicAdd(denom + (size_t)d * 4 + 2, e2);
        unsafeAtomicAdd(denom + (size_t)d * 4 + 3, e3);
    }
}

// ---------------------------------------------------------------------------
// Edge pass 2: out[d][:] += coef * Wx[s][:],
// coef = sum_h exp(e_h) / (denom[d][h] + 2e-9). Wave per edge.
// ---------------------------------------------------------------------------
__global__ __launch_bounds__(256) void k_edge_msg(
    const int* __restrict__ ei, const float* __restrict__ asrc,
    const float* __restrict__ adst, const float* __restrict__ denom,
    const float* __restrict__ Wx, float* __restrict__ out, int E)
{
    int tid = threadIdx.x;
    int lane = tid & 63;
    int gw = (blockIdx.x * blockDim.x + tid) >> 6;
    int waves = (gridDim.x * blockDim.x) >> 6;
    for (int e = gw; e < E; e += waves) {
        int eu = __builtin_amdgcn_readfirstlane(e);
        int s = ei[eu], d = ei[E + eu];
        float4 as = ((const float4*)asrc)[s];
        float4 ad = ((const float4*)adst)[d];
        float4 dn = ((const float4*)denom)[d];
        float coef = expf(lrelu02(as.x + ad.x)) / (dn.x + 2e-9f)
                   + expf(lrelu02(as.y + ad.y)) / (dn.y + 2e-9f)
                   + expf(lrelu02(as.z + ad.z)) / (dn.z + 2e-9f)
                   + expf(lrelu02(as.w + ad.w)) / (dn.w + 2e-9f);
        float w0 = Wx[(size_t)s * 128 + lane];
        float w1 = Wx[(size_t)s * 128 + 64 + lane];
        unsafeAtomicAdd(out + (size_t)d * 128 + lane, coef * w0);
        unsafeAtomicAdd(out + (size_t)d * 128 + 64 + lane, coef * w1);
    }
}

// out = elu(out / 4), in place, float4-vectorized.
__global__ __launch_bounds__(256) void k_elu(float4* __restrict__ buf, int n4)
{
    int stride = gridDim.x * blockDim.x;
    for (int i = blockIdx.x * blockDim.x + threadIdx.x; i < n4; i += stride) {
        float4 v = buf[i];
        v.x *= 0.25f; v.y *= 0.25f; v.z *= 0.25f; v.w *= 0.25f;
        v.x = v.x > 0.f ? v.x : expm1f(v.x);
        v.y = v.y > 0.f ? v.y : expm1f(v.y);
        v.z = v.z > 0.f ? v.z : expm1f(v.z);
        v.w = v.w > 0.f ? v.w : expm1f(v.w);
        buf[i] = v;
    }
}

// ---------------------------------------------------------------------------
// Fused ELU + FC head. Wave per node: x = elu(acc/4) (128), h = relu(x@fc1+b),
// out[n] = h@fc2 + b2. fc1 column in regs; x broadcast via readlane.
// ---------------------------------------------------------------------------
__global__ __launch_bounds__(256) void k_fc(
    const float* __restrict__ acc2, const float* __restrict__ fc1w,
    const float* __restrict__ fc1b, const float* __restrict__ fc2w,
    const float* __restrict__ fc2b, float* __restrict__ out, int N)
{
    int tid = threadIdx.x;
    int lane = tid & 63;
    int gw = (blockIdx.x * blockDim.x + tid) >> 6;
    int waves = (gridDim.x * blockDim.x) >> 6;
    float w1reg[128];
#pragma unroll
    for (int c = 0; c < 128; c++) w1reg[c] = fc1w[c * 64 + lane];
    float b1v = fc1b[lane];
    float w2 = fc2w[lane];
    float b2 = fc2b[0];
    for (int n = gw; n < N; n += waves) {
        float x0 = acc2[(size_t)n * 128 + lane] * 0.25f;
        float x1 = acc2[(size_t)n * 128 + 64 + lane] * 0.25f;
        x0 = x0 > 0.f ? x0 : expm1f(x0);
        x1 = x1 > 0.f ? x1 : expm1f(x1);
        float h = b1v;
#pragma unroll
        for (int c = 0; c < 64; c++) h += readl(x0, c) * w1reg[c];
#pragma unroll
        for (int c = 0; c < 64; c++) h += readl(x1, c) * w1reg[64 + c];
        float r = fmaxf(h, 0.0f) * w2;
#pragma unroll
        for (int off = 32; off; off >>= 1) r += __shfl_xor(r, off, 64);
        if (lane == 0) out[n] = r + b2;
    }
}

extern "C" void kernel_launch(void* const* d_in, const int* in_sizes, int n_in,
                              void* d_out, int out_size, void* d_ws, size_t ws_size,
                              hipStream_t stream)
{
    const float* nf   = (const float*)d_in[0];
    const int*   ei   = (const int*)  d_in[1];
    const float* ts   = (const float*)d_in[2];
    const float* Wih0 = (const float*)d_in[3];
    const float* Whh0 = (const float*)d_in[4];
    const float* b0   = (const float*)d_in[5];
    const float* Wih1 = (const float*)d_in[6];
    const float* Whh1 = (const float*)d_in[7];
    const float* b1   = (const float*)d_in[8];
    const float* W1   = (const float*)d_in[9];
    const float* A1   = (const float*)d_in[10];
    const float* W2   = (const float*)d_in[11];
    const float* A2   = (const float*)d_in[12];
    const float* fc1w = (const float*)d_in[13];
    const float* fc1b = (const float*)d_in[14];
    const float* fc2w = (const float*)d_in[15];
    const float* fc2b = (const float*)d_in[16];

    int N = in_sizes[0] / 16;
    int E = in_sizes[1] / 2;
    int T = in_sizes[2] / 3;

    char* ws = (char*)d_ws;
    float* tsb   = (float*)ws;                       // 128 floats
    float* asrc  = (float*)(ws + 4096);              // N*4
    float* adst  = asrc + (size_t)N * 4;             // N*4
    float* denom = adst + (size_t)N * 4;             // N*4
    size_t small_bytes = 4096 + (size_t)N * 12 * sizeof(float);
    small_bytes = (small_bytes + 511) & ~(size_t)511;
    float* bufA = (float*)(ws + small_bytes);        // N*128
    float* bufB = bufA + (size_t)N * 128;            // N*128

    // ---- LSTM + ts-embedding bias ----
    k_lstm<<<1, 512, 0, stream>>>(ts, Wih0, Whh0, b0, Wih1, Whh1, b1, W1, tsb, T);

    // ---- GAT layer 1 ----
    k_gemm<16><<<1024, 256, 0, stream>>>(nf, W1, tsb, bufA, N);
    k_att<<<1024, 256, 0, stream>>>(bufA, A1, asrc, adst, N);
    hipMemsetAsync(denom, 0, (size_t)N * 4 * sizeof(float), stream);
    hipMemsetAsync(bufB, 0, (size_t)N * 128 * sizeof(float), stream);
    k_edge_denom<<<2048, 256, 0, stream>>>(ei, asrc, adst, denom, E);
    k_edge_msg<<<4096, 256, 0, stream>>>(ei, asrc, adst, denom, bufA, bufB, E);
    k_elu<<<2048, 256, 0, stream>>>((float4*)bufB, N * 32);

    // ---- GAT layer 2 ----
    k_gemm<128><<<1024, 256, 0, stream>>>(bufB, W2, (const float*)nullptr, bufA, N);
    k_att<<<1024, 256, 0, stream>>>(bufA, A2, asrc, adst, N);
    hipMemsetAsync(denom, 0, (size_t)N * 4 * sizeof(float), stream);
    hipMemsetAsync(bufB, 0, (size_t)N * 128 * sizeof(float), stream);
    k_edge_denom<<<2048, 256, 0, stream>>>(ei, asrc, adst, denom, E);
    k_edge_msg<<<4096, 256, 0, stream>>>(ei, asrc, adst, denom, bufA, bufB, E);

    // ---- FC head (fused ELU) ----
    k_fc<<<1024, 256, 0, stream>>>(bufB, fc1w, fc1b, fc2w, fc2b, (float*)d_out, N);
}

// Round 2
// 1106.578 us; speedup vs baseline: 2.4168x; 2.4168x over previous
//
#include <hip/hip_runtime.h>
#include <math.h>

#define DEV __device__ __forceinline__

DEV float sigm(float x) { return 1.0f / (1.0f + expf(-x)); }
DEV float lrelu02(float x) { return x > 0.0f ? x : 0.2f * x; }
DEV float readl(float v, int l) {
    return __int_as_float(__builtin_amdgcn_readlane(__float_as_int(v), l));
}
DEV int readli(int v, int l) { return __builtin_amdgcn_readlane(v, l); }

// ---------------------------------------------------------------------------
// LSTM: 2 layers, H=64, sequential over T. One block of 512 threads.
// ---------------------------------------------------------------------------
__global__ __launch_bounds__(512) void k_lstm(
    const float* __restrict__ ts,
    const float* __restrict__ Wih0, const float* __restrict__ Whh0, const float* __restrict__ b0,
    const float* __restrict__ Wih1, const float* __restrict__ Whh1, const float* __restrict__ b1,
    const float* __restrict__ W1, float* __restrict__ tsb, int T)
{
    __shared__ __align__(16) float h0s[64], c0s[64], h1s[64], c1s[64];
    __shared__ float g0[256], g1[256];
    int tid = threadIdx.x;

    float wA[64], wB[64], wih[3], bias;
    if (tid < 256) {
        bias = b0[tid];
#pragma unroll
        for (int k = 0; k < 3; k++) wih[k] = Wih0[tid * 3 + k];
#pragma unroll
        for (int k = 0; k < 64; k++) wA[k] = Whh0[tid * 64 + k];
#pragma unroll
        for (int k = 0; k < 64; k++) wB[k] = 0.0f;
    } else {
        int j = tid - 256;
        bias = b1[j];
        wih[0] = wih[1] = wih[2] = 0.0f;
#pragma unroll
        for (int k = 0; k < 64; k++) wA[k] = Whh1[j * 64 + k];
#pragma unroll
        for (int k = 0; k < 64; k++) wB[k] = Wih1[j * 64 + k];
    }
    if (tid < 64) { h0s[tid] = 0.f; c0s[tid] = 0.f; h1s[tid] = 0.f; c1s[tid] = 0.f; }
    __syncthreads();

    for (int t = 0; t < T; ++t) {
        if (tid < 256) {
            float acc = bias + ts[t*3+0]*wih[0] + ts[t*3+1]*wih[1] + ts[t*3+2]*wih[2];
#pragma unroll
            for (int k = 0; k < 64; k += 4) {
                float4 hv = *(const float4*)&h0s[k];
                acc += hv.x*wA[k] + hv.y*wA[k+1] + hv.z*wA[k+2] + hv.w*wA[k+3];
            }
            g0[tid] = acc;
        } else {
            int j = tid - 256;
            float acc = bias;
#pragma unroll
            for (int k = 0; k < 64; k += 4) {
                float4 hv = *(const float4*)&h1s[k];
                acc += hv.x*wA[k] + hv.y*wA[k+1] + hv.z*wA[k+2] + hv.w*wA[k+3];
            }
            g1[j] = acc;
        }
        __syncthreads();
        if (tid < 64) {
            float i = sigm(g0[tid]), f = sigm(g0[tid+64]);
            float gg = tanhf(g0[tid+128]), o = sigm(g0[tid+192]);
            float c = f * c0s[tid] + i * gg;
            c0s[tid] = c; h0s[tid] = o * tanhf(c);
        }
        __syncthreads();
        if (tid >= 256) {
            int j = tid - 256;
            float acc = g1[j];
#pragma unroll
            for (int k = 0; k < 64; k += 4) {
                float4 hv = *(const float4*)&h0s[k];
                acc += hv.x*wB[k] + hv.y*wB[k+1] + hv.z*wB[k+2] + hv.w*wB[k+3];
            }
            g1[j] = acc;
        }
        __syncthreads();
        if (tid < 64) {
            float i = sigm(g1[tid]), f = sigm(g1[tid+64]);
            float gg = tanhf(g1[tid+128]), o = sigm(g1[tid+192]);
            float c = f * c1s[tid] + i * gg;
            c1s[tid] = c; h1s[tid] = o * tanhf(c);
        }
        __syncthreads();
    }
    if (tid < 128) {
        float acc = 0.f;
#pragma unroll
        for (int k = 0; k < 64; k++) acc += h1s[k] * W1[(16 + k) * 128 + tid];
        tsb[tid] = acc;
    }
}

// ---------------------------------------------------------------------------
// GEMM: Y[n][c] = bias[c] + sum_k X[n][k]*W[k][c], C=128 fixed.
// ---------------------------------------------------------------------------
template <int K>
__global__ __launch_bounds__(256) void k_gemm(
    const float* __restrict__ X, const float* __restrict__ W,
    const float* __restrict__ bias, float* __restrict__ Y, int N)
{
    int tid = threadIdx.x;
    int lane = tid & 63;
    int gw = (blockIdx.x * blockDim.x + tid) >> 6;
    int half = gw & 1;
    int col = lane + 64 * half;
    float wreg[K];
#pragma unroll
    for (int k = 0; k < K; k++) wreg[k] = W[k * 128 + col];
    float b = bias ? bias[col] : 0.0f;
    int total_waves = (gridDim.x * blockDim.x) >> 6;
    int nstride = total_waves >> 1;
    for (int n = (gw >> 1); n < N; n += nstride) {
        int nu = __builtin_amdgcn_readfirstlane(n);
        const float* xrow = X + (size_t)nu * K;
        float acc = b;
#pragma unroll
        for (int k = 0; k < K; k++) acc += xrow[k] * wreg[k];
        Y[(size_t)nu * 128 + col] = acc;
    }
}

// ---------------------------------------------------------------------------
// Attention projections: wave per node, shuffle-reduce 8 dots.
// ---------------------------------------------------------------------------
__global__ __launch_bounds__(256) void k_att(
    const float* __restrict__ Wx, const float* __restrict__ A,
    float* __restrict__ asrc, float* __restrict__ adst, int N)
{
    int tid = threadIdx.x;
    int lane = tid & 63;
    int gw = (blockIdx.x * blockDim.x + tid) >> 6;
    int waves = (gridDim.x * blockDim.x) >> 6;
    float4 s0 = ((const float4*)A)[lane];
    float4 s1 = ((const float4*)A)[lane + 64];
    float4 d0 = ((const float4*)A)[lane + 128];
    float4 d1 = ((const float4*)A)[lane + 192];
    for (int n = gw; n < N; n += waves) {
        float w0 = Wx[(size_t)n * 128 + lane];
        float w1 = Wx[(size_t)n * 128 + 64 + lane];
        float as[4], ad[4];
        as[0] = w0*s0.x + w1*s1.x; as[1] = w0*s0.y + w1*s1.y;
        as[2] = w0*s0.z + w1*s1.z; as[3] = w0*s0.w + w1*s1.w;
        ad[0] = w0*d0.x + w1*d1.x; ad[1] = w0*d0.y + w1*d1.y;
        ad[2] = w0*d0.z + w1*d1.z; ad[3] = w0*d0.w + w1*d1.w;
#pragma unroll
        for (int off = 32; off; off >>= 1) {
#pragma unroll
            for (int h = 0; h < 4; h++) {
                as[h] += __shfl_xor(as[h], off, 64);
                ad[h] += __shfl_xor(ad[h], off, 64);
            }
        }
        if (lane == 0) {
            float4 o1; o1.x = as[0]; o1.y = as[1]; o1.z = as[2]; o1.w = as[3];
            float4 o2; o2.x = ad[0]; o2.y = ad[1]; o2.z = ad[2]; o2.w = ad[3];
            ((float4*)asrc)[n] = o1;
            ((float4*)adst)[n] = o2;
        }
    }
}

// ---------------------------------------------------------------------------
// CSR build: degree histogram -> exclusive scan -> scatter src ids.
// ---------------------------------------------------------------------------
__global__ __launch_bounds__(256) void k_deg(
    const int* __restrict__ ei, int* __restrict__ deg, int E)
{
    int stride = gridDim.x * blockDim.x;
    for (int e = blockIdx.x * blockDim.x + threadIdx.x; e < E; e += stride)
        atomicAdd(&deg[ei[E + e]], 1);
}

// Block scans 1024 elements (256 thr x 4); writes block-local exclusive + block sum.
__global__ __launch_bounds__(256) void k_scan1(
    const int* __restrict__ deg, int* __restrict__ excl, int* __restrict__ bsum, int N)
{
    int tid = threadIdx.x;
    int base = blockIdx.x * 1024 + tid * 4;
    int d0 = base + 0 < N ? deg[base + 0] : 0;
    int d1 = base + 1 < N ? deg[base + 1] : 0;
    int d2 = base + 2 < N ? deg[base + 2] : 0;
    int d3 = base + 3 < N ? deg[base + 3] : 0;
    int tsum = d0 + d1 + d2 + d3;
    int lane = tid & 63, wid = tid >> 6;
    int incl = tsum;
#pragma unroll
    for (int off = 1; off < 64; off <<= 1) {
        int t = __shfl_up(incl, off, 64);
        if (lane >= off) incl += t;
    }
    __shared__ int wsum[4];
    if (lane == 63) wsum[wid] = incl;
    __syncthreads();
    int woff = 0;
#pragma unroll
    for (int w = 0; w < 4; w++) if (w < wid) woff += wsum[w];
    int tex = woff + incl - tsum;
    if (base + 0 < N) excl[base + 0] = tex;
    if (base + 1 < N) excl[base + 1] = tex + d0;
    if (base + 2 < N) excl[base + 2] = tex + d0 + d1;
    if (base + 3 < N) excl[base + 3] = tex + d0 + d1 + d2;
    if (tid == 255) bsum[blockIdx.x] = woff + incl;
}

// Single block: exclusive scan of up to 256 block sums.
__global__ __launch_bounds__(256) void k_scan2(int* __restrict__ bsum, int nb)
{
    __shared__ int tmp[256];
    int tid = threadIdx.x;
    int v = tid < nb ? bsum[tid] : 0;
    tmp[tid] = v;
    __syncthreads();
    for (int off = 1; off < 256; off <<= 1) {
        int t = (tid >= off) ? tmp[tid - off] : 0;
        __syncthreads();
        tmp[tid] += t;
        __syncthreads();
    }
    if (tid < nb) bsum[tid] = tmp[tid] - v;
}

__global__ __launch_bounds__(256) void k_scan3(
    int* __restrict__ excl, const int* __restrict__ bsum,
    int* __restrict__ rowptr, int* __restrict__ fill, int N, int E)
{
    int tid = threadIdx.x;
    int base = blockIdx.x * 1024 + tid * 4;
    int off = bsum[blockIdx.x];
#pragma unroll
    for (int i = 0; i < 4; i++) {
        int idx = base + i;
        if (idx < N) {
            int v = excl[idx] + off;
            rowptr[idx] = v;
            fill[idx] = v;
        }
    }
    if (blockIdx.x == 0 && tid == 0) rowptr[N] = E;
}

__global__ __launch_bounds__(256) void k_scatter(
    const int* __restrict__ ei, int* __restrict__ fill, int* __restrict__ esrc, int E)
{
    int stride = gridDim.x * blockDim.x;
    for (int e = blockIdx.x * blockDim.x + threadIdx.x; e < E; e += stride) {
        int s = ei[e], d = ei[E + e];
        int pos = atomicAdd(&fill[d], 1);
        esrc[pos] = s;
    }
}

// ---------------------------------------------------------------------------
// Fused GAT aggregate, CSR gather form. Wave per dst node:
//   pass A (lane-parallel over edges): denom[h] = sum exp(lrelu(asrc[s]+adst[d]))
//   pass B: per-lane coef, then serial-broadcast accumulate of Wx rows.
// Writes each output row exactly once (no atomics, no pre-zeroing).
// ---------------------------------------------------------------------------
template <int DO_ELU>
__global__ __launch_bounds__(256) void k_msg_csr(
    const int* __restrict__ rowptr, const int* __restrict__ esrc,
    const float* __restrict__ asrc, const float* __restrict__ adst,
    const float* __restrict__ Wx, float* __restrict__ out, int N)
{
    int tid = threadIdx.x;
    int lane = tid & 63;
    int gw = (blockIdx.x * blockDim.x + tid) >> 6;
    int waves = (gridDim.x * blockDim.x) >> 6;
    for (int n = gw; n < N; n += waves) {
        int nu = __builtin_amdgcn_readfirstlane(n);
        int beg = rowptr[nu], end = rowptr[nu + 1];
        float4 ad = ((const float4*)adst)[nu];
        float den0 = 0.f, den1 = 0.f, den2 = 0.f, den3 = 0.f;
        for (int c = beg; c < end; c += 64) {
            int e = c + lane;
            bool valid = e < end;
            int s = valid ? esrc[e] : 0;
            float4 as = ((const float4*)asrc)[s];
            if (valid) {
                den0 += expf(lrelu02(as.x + ad.x));
                den1 += expf(lrelu02(as.y + ad.y));
                den2 += expf(lrelu02(as.z + ad.z));
                den3 += expf(lrelu02(as.w + ad.w));
            }
        }
#pragma unroll
        for (int off = 32; off; off >>= 1) {
            den0 += __shfl_xor(den0, off, 64);
            den1 += __shfl_xor(den1, off, 64);
            den2 += __shfl_xor(den2, off, 64);
            den3 += __shfl_xor(den3, off, 64);
        }
        den0 += 2e-9f; den1 += 2e-9f; den2 += 2e-9f; den3 += 2e-9f;

        float acc0 = 0.f, acc1 = 0.f;
        for (int c = beg; c < end; c += 64) {
            int e = c + lane;
            bool valid = e < end;
            int s = valid ? esrc[e] : 0;
            float4 as = ((const float4*)asrc)[s];
            float coef = 0.f;
            if (valid) {
                coef = expf(lrelu02(as.x + ad.x)) / den0
                     + expf(lrelu02(as.y + ad.y)) / den1
                     + expf(lrelu02(as.z + ad.z)) / den2
                     + expf(lrelu02(as.w + ad.w)) / den3;
            }
            int ne = min(64, end - c);
            for (int j = 0; j < ne; ++j) {
                int sj = readli(s, j);
                float cj = readl(coef, j);
                const float* wrow = Wx + (size_t)sj * 128;
                acc0 = fmaf(cj, wrow[lane], acc0);
                acc1 = fmaf(cj, wrow[64 + lane], acc1);
            }
        }
        if (DO_ELU) {
            acc0 *= 0.25f; acc1 *= 0.25f;
            acc0 = acc0 > 0.f ? acc0 : expm1f(acc0);
            acc1 = acc1 > 0.f ? acc1 : expm1f(acc1);
        }
        out[(size_t)nu * 128 + lane] = acc0;
        out[(size_t)nu * 128 + 64 + lane] = acc1;
    }
}

// ---------------------------------------------------------------------------
// Fused ELU + FC head. Wave per node.
// ---------------------------------------------------------------------------
__global__ __launch_bounds__(256) void k_fc(
    const float* __restrict__ acc2, const float* __restrict__ fc1w,
    const float* __restrict__ fc1b, const float* __restrict__ fc2w,
    const float* __restrict__ fc2b, float* __restrict__ out, int N)
{
    int tid = threadIdx.x;
    int lane = tid & 63;
    int gw = (blockIdx.x * blockDim.x + tid) >> 6;
    int waves = (gridDim.x * blockDim.x) >> 6;
    float w1reg[128];
#pragma unroll
    for (int c = 0; c < 128; c++) w1reg[c] = fc1w[c * 64 + lane];
    float b1v = fc1b[lane];
    float w2 = fc2w[lane];
    float b2 = fc2b[0];
    for (int n = gw; n < N; n += waves) {
        float x0 = acc2[(size_t)n * 128 + lane] * 0.25f;
        float x1 = acc2[(size_t)n * 128 + 64 + lane] * 0.25f;
        x0 = x0 > 0.f ? x0 : expm1f(x0);
        x1 = x1 > 0.f ? x1 : expm1f(x1);
        float h = b1v;
#pragma unroll
        for (int c = 0; c < 64; c++) h += readl(x0, c) * w1reg[c];
#pragma unroll
        for (int c = 0; c < 64; c++) h += readl(x1, c) * w1reg[64 + c];
        float r = fmaxf(h, 0.0f) * w2;
#pragma unroll
        for (int off = 32; off; off >>= 1) r += __shfl_xor(r, off, 64);
        if (lane == 0) out[n] = r + b2;
    }
}

extern "C" void kernel_launch(void* const* d_in, const int* in_sizes, int n_in,
                              void* d_out, int out_size, void* d_ws, size_t ws_size,
                              hipStream_t stream)
{
    const float* nf   = (const float*)d_in[0];
    const int*   ei   = (const int*)  d_in[1];
    const float* ts   = (const float*)d_in[2];
    const float* Wih0 = (const float*)d_in[3];
    const float* Whh0 = (const float*)d_in[4];
    const float* b0   = (const float*)d_in[5];
    const float* Wih1 = (const float*)d_in[6];
    const float* Whh1 = (const float*)d_in[7];
    const float* b1   = (const float*)d_in[8];
    const float* W1   = (const float*)d_in[9];
    const float* A1   = (const float*)d_in[10];
    const float* W2   = (const float*)d_in[11];
    const float* A2   = (const float*)d_in[12];
    const float* fc1w = (const float*)d_in[13];
    const float* fc1b = (const float*)d_in[14];
    const float* fc2w = (const float*)d_in[15];
    const float* fc2b = (const float*)d_in[16];

    int N = in_sizes[0] / 16;
    int E = in_sizes[1] / 2;
    int T = in_sizes[2] / 3;

    char* ws = (char*)d_ws;
    size_t off = 0;
    auto alloc = [&](size_t bytes) {
        char* p = ws + off;
        off = (off + bytes + 255) & ~(size_t)255;
        return p;
    };
    float* tsb    = (float*)alloc(512);
    float* asrc   = (float*)alloc((size_t)N * 4 * sizeof(float));
    float* adst   = (float*)alloc((size_t)N * 4 * sizeof(float));
    int*   rowptr = (int*)  alloc((size_t)(N + 1) * sizeof(int));
    int*   esrc   = (int*)  alloc((size_t)E * sizeof(int));
    int*   degfil = (int*)  alloc((size_t)N * sizeof(int));   // deg, then fill
    int*   bsum   = (int*)  alloc(256 * sizeof(int));
    float* bufA   = (float*)alloc((size_t)N * 128 * sizeof(float));
    float* bufB   = (float*)alloc((size_t)N * 128 * sizeof(float));

    int nb_scan = (N + 1023) / 1024;

    // ---- LSTM + ts-embedding bias ----
    k_lstm<<<1, 512, 0, stream>>>(ts, Wih0, Whh0, b0, Wih1, Whh1, b1, W1, tsb, T);

    // ---- CSR build (once, reused by both GAT layers) ----
    hipMemsetAsync(degfil, 0, (size_t)N * sizeof(int), stream);
    k_deg<<<2048, 256, 0, stream>>>(ei, degfil, E);
    k_scan1<<<nb_scan, 256, 0, stream>>>(degfil, rowptr, bsum, N);
    k_scan2<<<1, 256, 0, stream>>>(bsum, nb_scan);
    k_scan3<<<nb_scan, 256, 0, stream>>>(rowptr, bsum, rowptr, degfil, N, E);
    k_scatter<<<2048, 256, 0, stream>>>(ei, degfil, esrc, E);

    // ---- GAT layer 1 ----
    k_gemm<16><<<1024, 256, 0, stream>>>(nf, W1, tsb, bufA, N);
    k_att<<<1024, 256, 0, stream>>>(bufA, A1, asrc, adst, N);
    k_msg_csr<1><<<4096, 256, 0, stream>>>(rowptr, esrc, asrc, adst, bufA, bufB, N);

    // ---- GAT layer 2 ----
    k_gemm<128><<<1024, 256, 0, stream>>>(bufB, W2, (const float*)nullptr, bufA, N);
    k_att<<<1024, 256, 0, stream>>>(bufA, A2, asrc, adst, N);
    k_msg_csr<0><<<4096, 256, 0, stream>>>(rowptr, esrc, asrc, adst, bufA, bufB, N);

    // ---- FC head (fused ELU) ----
    k_fc<<<1024, 256, 0, stream>>>(bufB, fc1w, fc1b, fc2w, fc2b, (float*)d_out, N);
}

// Round 3
// 1002.501 us; speedup vs baseline: 2.6677x; 1.1038x over previous
//
#include <hip/hip_runtime.h>
#include <math.h>

#define DEV __device__ __forceinline__

#define LOG2E 1.4426950408889634f

DEV float fexp(float x)  { return __builtin_amdgcn_exp2f(LOG2E * x); }
DEV float fsigm(float x) { return __builtin_amdgcn_rcpf(1.0f + __builtin_amdgcn_exp2f(-LOG2E * x)); }
DEV float ftanh(float x) { return 1.0f - 2.0f * __builtin_amdgcn_rcpf(__builtin_amdgcn_exp2f(2.0f * LOG2E * x) + 1.0f); }
DEV float lrelu02(float x) { return x > 0.0f ? x : 0.2f * x; }
DEV float readl(float v, int l) {
    return __int_as_float(__builtin_amdgcn_readlane(__float_as_int(v), l));
}
DEV int readli(int v, int l) { return __builtin_amdgcn_readlane(v, l); }

// ---------------------------------------------------------------------------
// LSTM input projection, parallel over all timesteps:
// xg0[t][g] = b0[g] + sum_{k<3} ts[t*3+k] * Wih0[g*3+k]
// ---------------------------------------------------------------------------
__global__ __launch_bounds__(256) void k_lstm_pre(
    const float* __restrict__ ts, const float* __restrict__ Wih0,
    const float* __restrict__ b0, float* __restrict__ xg0, int T)
{
    int idx = blockIdx.x * 256 + threadIdx.x;
    int t = idx >> 8, g = idx & 255;
    if (t < T)
        xg0[idx] = b0[g] + ts[t*3+0]*Wih0[g*3+0] + ts[t*3+1]*Wih0[g*3+1]
                 + ts[t*3+2]*Wih0[g*3+2];
}

// ---------------------------------------------------------------------------
// LSTM: 2 layers, H=64, software-pipelined (layer 1 runs one step behind
// layer 0), 2 syncthreads per step. Waves 0-3: layer-0 gates for step k.
// Waves 4-7: layer-1 gates for step k-1 (h0(k-1), h1(k-2) both ready).
// Activations: wave 0 (l0) and wave 4 (l1) in parallel, c-state in registers.
// Epilogue: tsb[c] = sum_k h1[k]*W1[16+k][c].
// ---------------------------------------------------------------------------
__global__ __launch_bounds__(512) void k_lstm2(
    const float* __restrict__ xg0,
    const float* __restrict__ Wih1, const float* __restrict__ Whh1, const float* __restrict__ b1,
    const float* __restrict__ Whh0,
    const float* __restrict__ W1, float* __restrict__ tsb, int T)
{
    __shared__ __align__(16) float h0s[64], h1s[64];
    __shared__ float g0[256], g1[256];
    int tid = threadIdx.x;
    bool lo = tid < 256;
    int j = tid & 255;

    float wA[64], wB[64], bias;
    if (lo) {
        bias = 0.0f;
#pragma unroll
        for (int k = 0; k < 64; k++) wA[k] = Whh0[j * 64 + k];
#pragma unroll
        for (int k = 0; k < 64; k++) wB[k] = 0.0f;
    } else {
        bias = b1[j];
#pragma unroll
        for (int k = 0; k < 64; k++) wA[k] = Whh1[j * 64 + k];
#pragma unroll
        for (int k = 0; k < 64; k++) wB[k] = Wih1[j * 64 + k];
    }
    if (tid < 64) { h0s[tid] = 0.f; h1s[tid] = 0.f; }
    float creg = 0.0f;   // c0 in lanes of wave 0, c1 in lanes of wave 4
    __syncthreads();

    for (int k = 0; k <= T; ++k) {
        if (lo) {
            if (k < T) {
                float acc = xg0[k * 256 + j];
#pragma unroll
                for (int q = 0; q < 64; q += 4) {
                    float4 hv = *(const float4*)&h0s[q];
                    acc = fmaf(hv.x, wA[q],   acc);
                    acc = fmaf(hv.y, wA[q+1], acc);
                    acc = fmaf(hv.z, wA[q+2], acc);
                    acc = fmaf(hv.w, wA[q+3], acc);
                }
                g0[j] = acc;
            }
        } else {
            if (k >= 1) {
                float acc = bias;
#pragma unroll
                for (int q = 0; q < 64; q += 4) {
                    float4 h1v = *(const float4*)&h1s[q];
                    float4 h0v = *(const float4*)&h0s[q];
                    acc = fmaf(h1v.x, wA[q],   acc);
                    acc = fmaf(h1v.y, wA[q+1], acc);
                    acc = fmaf(h1v.z, wA[q+2], acc);
                    acc = fmaf(h1v.w, wA[q+3], acc);
                    acc = fmaf(h0v.x, wB[q],   acc);
                    acc = fmaf(h0v.y, wB[q+1], acc);
                    acc = fmaf(h0v.z, wB[q+2], acc);
                    acc = fmaf(h0v.w, wB[q+3], acc);
                }
                g1[j] = acc;
            }
        }
        __syncthreads();
        if (tid < 64) {
            if (k < T) {
                float i = fsigm(g0[tid]), f = fsigm(g0[tid+64]);
                float gg = ftanh(g0[tid+128]), o = fsigm(g0[tid+192]);
                creg = f * creg + i * gg;
                h0s[tid] = o * ftanh(creg);
            }
        } else if (tid >= 256 && tid < 320) {
            if (k >= 1) {
                int l = tid - 256;
                float i = fsigm(g1[l]), f = fsigm(g1[l+64]);
                float gg = ftanh(g1[l+128]), o = fsigm(g1[l+192]);
                creg = f * creg + i * gg;
                h1s[l] = o * ftanh(creg);
            }
        }
        __syncthreads();
    }
    if (tid < 128) {
        float acc = 0.f;
#pragma unroll
        for (int k = 0; k < 64; k++) acc += h1s[k] * W1[(16 + k) * 128 + tid];
        tsb[tid] = acc;
    }
}

// ---------------------------------------------------------------------------
// GEMM: Y[n][c] = bias[c] + sum_k X[n][k]*W[k][c], C=128 fixed.
// ---------------------------------------------------------------------------
template <int K>
__global__ __launch_bounds__(256) void k_gemm(
    const float* __restrict__ X, const float* __restrict__ W,
    const float* __restrict__ bias, float* __restrict__ Y, int N)
{
    int tid = threadIdx.x;
    int lane = tid & 63;
    int gw = (blockIdx.x * blockDim.x + tid) >> 6;
    int half = gw & 1;
    int col = lane + 64 * half;
    float wreg[K];
#pragma unroll
    for (int k = 0; k < K; k++) wreg[k] = W[k * 128 + col];
    float b = bias ? bias[col] : 0.0f;
    int total_waves = (gridDim.x * blockDim.x) >> 6;
    int nstride = total_waves >> 1;
    for (int n = (gw >> 1); n < N; n += nstride) {
        int nu = __builtin_amdgcn_readfirstlane(n);
        const float* xrow = X + (size_t)nu * K;
        float acc = b;
#pragma unroll
        for (int k = 0; k < K; k++) acc += xrow[k] * wreg[k];
        Y[(size_t)nu * 128 + col] = acc;
    }
}

// ---------------------------------------------------------------------------
// Attention projections: wave per node, shuffle-reduce 8 dots.
// ---------------------------------------------------------------------------
__global__ __launch_bounds__(256) void k_att(
    const float* __restrict__ Wx, const float* __restrict__ A,
    float* __restrict__ asrc, float* __restrict__ adst, int N)
{
    int tid = threadIdx.x;
    int lane = tid & 63;
    int gw = (blockIdx.x * blockDim.x + tid) >> 6;
    int waves = (gridDim.x * blockDim.x) >> 6;
    float4 s0 = ((const float4*)A)[lane];
    float4 s1 = ((const float4*)A)[lane + 64];
    float4 d0 = ((const float4*)A)[lane + 128];
    float4 d1 = ((const float4*)A)[lane + 192];
    for (int n = gw; n < N; n += waves) {
        float w0 = Wx[(size_t)n * 128 + lane];
        float w1 = Wx[(size_t)n * 128 + 64 + lane];
        float as[4], ad[4];
        as[0] = w0*s0.x + w1*s1.x; as[1] = w0*s0.y + w1*s1.y;
        as[2] = w0*s0.z + w1*s1.z; as[3] = w0*s0.w + w1*s1.w;
        ad[0] = w0*d0.x + w1*d1.x; ad[1] = w0*d0.y + w1*d1.y;
        ad[2] = w0*d0.z + w1*d1.z; ad[3] = w0*d0.w + w1*d1.w;
#pragma unroll
        for (int off = 32; off; off >>= 1) {
#pragma unroll
            for (int h = 0; h < 4; h++) {
                as[h] += __shfl_xor(as[h], off, 64);
                ad[h] += __shfl_xor(ad[h], off, 64);
            }
        }
        if (lane == 0) {
            float4 o1; o1.x = as[0]; o1.y = as[1]; o1.z = as[2]; o1.w = as[3];
            float4 o2; o2.x = ad[0]; o2.y = ad[1]; o2.z = ad[2]; o2.w = ad[3];
            ((float4*)asrc)[n] = o1;
            ((float4*)adst)[n] = o2;
        }
    }
}

// ---------------------------------------------------------------------------
// CSR build: degree histogram -> exclusive scan -> scatter src ids.
// ---------------------------------------------------------------------------
__global__ __launch_bounds__(256) void k_deg(
    const int* __restrict__ ei, int* __restrict__ deg, int E)
{
    int stride = gridDim.x * blockDim.x;
    for (int e = blockIdx.x * blockDim.x + threadIdx.x; e < E; e += stride)
        atomicAdd(&deg[ei[E + e]], 1);
}

__global__ __launch_bounds__(256) void k_scan1(
    const int* __restrict__ deg, int* __restrict__ excl, int* __restrict__ bsum, int N)
{
    int tid = threadIdx.x;
    int base = blockIdx.x * 1024 + tid * 4;
    int d0 = base + 0 < N ? deg[base + 0] : 0;
    int d1 = base + 1 < N ? deg[base + 1] : 0;
    int d2 = base + 2 < N ? deg[base + 2] : 0;
    int d3 = base + 3 < N ? deg[base + 3] : 0;
    int tsum = d0 + d1 + d2 + d3;
    int lane = tid & 63, wid = tid >> 6;
    int incl = tsum;
#pragma unroll
    for (int off = 1; off < 64; off <<= 1) {
        int t = __shfl_up(incl, off, 64);
        if (lane >= off) incl += t;
    }
    __shared__ int wsum[4];
    if (lane == 63) wsum[wid] = incl;
    __syncthreads();
    int woff = 0;
#pragma unroll
    for (int w = 0; w < 4; w++) if (w < wid) woff += wsum[w];
    int tex = woff + incl - tsum;
    if (base + 0 < N) excl[base + 0] = tex;
    if (base + 1 < N) excl[base + 1] = tex + d0;
    if (base + 2 < N) excl[base + 2] = tex + d0 + d1;
    if (base + 3 < N) excl[base + 3] = tex + d0 + d1 + d2;
    if (tid == 255) bsum[blockIdx.x] = woff + incl;
}

__global__ __launch_bounds__(256) void k_scan2(int* __restrict__ bsum, int nb)
{
    __shared__ int tmp[256];
    int tid = threadIdx.x;
    int v = tid < nb ? bsum[tid] : 0;
    tmp[tid] = v;
    __syncthreads();
    for (int off = 1; off < 256; off <<= 1) {
        int t = (tid >= off) ? tmp[tid - off] : 0;
        __syncthreads();
        tmp[tid] += t;
        __syncthreads();
    }
    if (tid < nb) bsum[tid] = tmp[tid] - v;
}

__global__ __launch_bounds__(256) void k_scan3(
    int* __restrict__ excl, const int* __restrict__ bsum,
    int* __restrict__ rowptr, int* __restrict__ fill, int N, int E)
{
    int tid = threadIdx.x;
    int base = blockIdx.x * 1024 + tid * 4;
    int off = bsum[blockIdx.x];
#pragma unroll
    for (int i = 0; i < 4; i++) {
        int idx = base + i;
        if (idx < N) {
            int v = excl[idx] + off;
            rowptr[idx] = v;
            fill[idx] = v;
        }
    }
    if (blockIdx.x == 0 && tid == 0) rowptr[N] = E;
}

__global__ __launch_bounds__(256) void k_scatter(
    const int* __restrict__ ei, int* __restrict__ fill, int* __restrict__ esrc, int E)
{
    int stride = gridDim.x * blockDim.x;
    for (int e = blockIdx.x * blockDim.x + threadIdx.x; e < E; e += stride) {
        int s = ei[e], d = ei[E + e];
        int pos = atomicAdd(&fill[d], 1);
        esrc[pos] = s;
    }
}

// ---------------------------------------------------------------------------
// Fused GAT aggregate, CSR gather form. Wave per dst node.
// ---------------------------------------------------------------------------
template <int DO_ELU>
__global__ __launch_bounds__(256) void k_msg_csr(
    const int* __restrict__ rowptr, const int* __restrict__ esrc,
    const float* __restrict__ asrc, const float* __restrict__ adst,
    const float* __restrict__ Wx, float* __restrict__ out, int N)
{
    int tid = threadIdx.x;
    int lane = tid & 63;
    int gw = (blockIdx.x * blockDim.x + tid) >> 6;
    int waves = (gridDim.x * blockDim.x) >> 6;
    for (int n = gw; n < N; n += waves) {
        int nu = __builtin_amdgcn_readfirstlane(n);
        int beg = rowptr[nu], end = rowptr[nu + 1];
        float4 ad = ((const float4*)adst)[nu];
        float den0 = 0.f, den1 = 0.f, den2 = 0.f, den3 = 0.f;
        for (int c = beg; c < end; c += 64) {
            int e = c + lane;
            bool valid = e < end;
            int s = valid ? esrc[e] : 0;
            float4 as = ((const float4*)asrc)[s];
            if (valid) {
                den0 += fexp(lrelu02(as.x + ad.x));
                den1 += fexp(lrelu02(as.y + ad.y));
                den2 += fexp(lrelu02(as.z + ad.z));
                den3 += fexp(lrelu02(as.w + ad.w));
            }
        }
#pragma unroll
        for (int off = 32; off; off >>= 1) {
            den0 += __shfl_xor(den0, off, 64);
            den1 += __shfl_xor(den1, off, 64);
            den2 += __shfl_xor(den2, off, 64);
            den3 += __shfl_xor(den3, off, 64);
        }
        den0 = __builtin_amdgcn_rcpf(den0 + 2e-9f);
        den1 = __builtin_amdgcn_rcpf(den1 + 2e-9f);
        den2 = __builtin_amdgcn_rcpf(den2 + 2e-9f);
        den3 = __builtin_amdgcn_rcpf(den3 + 2e-9f);

        float acc0 = 0.f, acc1 = 0.f;
        for (int c = beg; c < end; c += 64) {
            int e = c + lane;
            bool valid = e < end;
            int s = valid ? esrc[e] : 0;
            float4 as = ((const float4*)asrc)[s];
            float coef = 0.f;
            if (valid) {
                coef = fexp(lrelu02(as.x + ad.x)) * den0
                     + fexp(lrelu02(as.y + ad.y)) * den1
                     + fexp(lrelu02(as.z + ad.z)) * den2
                     + fexp(lrelu02(as.w + ad.w)) * den3;
            }
            int ne = min(64, end - c);
            for (int j = 0; j < ne; ++j) {
                int sj = readli(s, j);
                float cj = readl(coef, j);
                const float* wrow = Wx + (size_t)sj * 128;
                acc0 = fmaf(cj, wrow[lane], acc0);
                acc1 = fmaf(cj, wrow[64 + lane], acc1);
            }
        }
        if (DO_ELU) {
            acc0 *= 0.25f; acc1 *= 0.25f;
            acc0 = acc0 > 0.f ? acc0 : expm1f(acc0);
            acc1 = acc1 > 0.f ? acc1 : expm1f(acc1);
        }
        out[(size_t)nu * 128 + lane] = acc0;
        out[(size_t)nu * 128 + 64 + lane] = acc1;
    }
}

// ---------------------------------------------------------------------------
// Fused ELU + FC head. Wave per node.
// ---------------------------------------------------------------------------
__global__ __launch_bounds__(256) void k_fc(
    const float* __restrict__ acc2, const float* __restrict__ fc1w,
    const float* __restrict__ fc1b, const float* __restrict__ fc2w,
    const float* __restrict__ fc2b, float* __restrict__ out, int N)
{
    int tid = threadIdx.x;
    int lane = tid & 63;
    int gw = (blockIdx.x * blockDim.x + tid) >> 6;
    int waves = (gridDim.x * blockDim.x) >> 6;
    float w1reg[128];
#pragma unroll
    for (int c = 0; c < 128; c++) w1reg[c] = fc1w[c * 64 + lane];
    float b1v = fc1b[lane];
    float w2 = fc2w[lane];
    float b2 = fc2b[0];
    for (int n = gw; n < N; n += waves) {
        float x0 = acc2[(size_t)n * 128 + lane] * 0.25f;
        float x1 = acc2[(size_t)n * 128 + 64 + lane] * 0.25f;
        x0 = x0 > 0.f ? x0 : expm1f(x0);
        x1 = x1 > 0.f ? x1 : expm1f(x1);
        float h = b1v;
#pragma unroll
        for (int c = 0; c < 64; c++) h += readl(x0, c) * w1reg[c];
#pragma unroll
        for (int c = 0; c < 64; c++) h += readl(x1, c) * w1reg[64 + c];
        float r = fmaxf(h, 0.0f) * w2;
#pragma unroll
        for (int off = 32; off; off >>= 1) r += __shfl_xor(r, off, 64);
        if (lane == 0) out[n] = r + b2;
    }
}

extern "C" void kernel_launch(void* const* d_in, const int* in_sizes, int n_in,
                              void* d_out, int out_size, void* d_ws, size_t ws_size,
                              hipStream_t stream)
{
    const float* nf   = (const float*)d_in[0];
    const int*   ei   = (const int*)  d_in[1];
    const float* ts   = (const float*)d_in[2];
    const float* Wih0 = (const float*)d_in[3];
    const float* Whh0 = (const float*)d_in[4];
    const float* b0   = (const float*)d_in[5];
    const float* Wih1 = (const float*)d_in[6];
    const float* Whh1 = (const float*)d_in[7];
    const float* b1   = (const float*)d_in[8];
    const float* W1   = (const float*)d_in[9];
    const float* A1   = (const float*)d_in[10];
    const float* W2   = (const float*)d_in[11];
    const float* A2   = (const float*)d_in[12];
    const float* fc1w = (const float*)d_in[13];
    const float* fc1b = (const float*)d_in[14];
    const float* fc2w = (const float*)d_in[15];
    const float* fc2b = (const float*)d_in[16];

    int N = in_sizes[0] / 16;
    int E = in_sizes[1] / 2;
    int T = in_sizes[2] / 3;

    char* ws = (char*)d_ws;
    size_t off = 0;
    auto alloc = [&](size_t bytes) {
        char* p = ws + off;
        off = (off + bytes + 255) & ~(size_t)255;
        return p;
    };
    float* tsb    = (float*)alloc(512);
    float* xg0    = (float*)alloc((size_t)T * 256 * sizeof(float));
    float* asrc   = (float*)alloc((size_t)N * 4 * sizeof(float));
    float* adst   = (float*)alloc((size_t)N * 4 * sizeof(float));
    int*   rowptr = (int*)  alloc((size_t)(N + 1) * sizeof(int));
    int*   esrc   = (int*)  alloc((size_t)E * sizeof(int));
    int*   degfil = (int*)  alloc((size_t)N * sizeof(int));
    int*   bsum   = (int*)  alloc(256 * sizeof(int));
    float* bufA   = (float*)alloc((size_t)N * 128 * sizeof(float));
    float* bufB   = (float*)alloc((size_t)N * 128 * sizeof(float));

    int nb_scan = (N + 1023) / 1024;

    // ---- LSTM (input proj parallel, recurrence pipelined) ----
    k_lstm_pre<<<T, 256, 0, stream>>>(ts, Wih0, b0, xg0, T);
    k_lstm2<<<1, 512, 0, stream>>>(xg0, Wih1, Whh1, b1, Whh0, W1, tsb, T);

    // ---- CSR build (once, reused by both GAT layers) ----
    hipMemsetAsync(degfil, 0, (size_t)N * sizeof(int), stream);
    k_deg<<<2048, 256, 0, stream>>>(ei, degfil, E);
    k_scan1<<<nb_scan, 256, 0, stream>>>(degfil, rowptr, bsum, N);
    k_scan2<<<1, 256, 0, stream>>>(bsum, nb_scan);
    k_scan3<<<nb_scan, 256, 0, stream>>>(rowptr, bsum, rowptr, degfil, N, E);
    k_scatter<<<2048, 256, 0, stream>>>(ei, degfil, esrc, E);

    // ---- GAT layer 1 ----
    k_gemm<16><<<1024, 256, 0, stream>>>(nf, W1, tsb, bufA, N);
    k_att<<<1024, 256, 0, stream>>>(bufA, A1, asrc, adst, N);
    k_msg_csr<1><<<4096, 256, 0, stream>>>(rowptr, esrc, asrc, adst, bufA, bufB, N);

    // ---- GAT layer 2 ----
    k_gemm<128><<<1024, 256, 0, stream>>>(bufB, W2, (const float*)nullptr, bufA, N);
    k_att<<<1024, 256, 0, stream>>>(bufA, A2, asrc, adst, N);
    k_msg_csr<0><<<4096, 256, 0, stream>>>(rowptr, esrc, asrc, adst, bufA, bufB, N);

    // ---- FC head (fused ELU) ----
    k_fc<<<1024, 256, 0, stream>>>(bufB, fc1w, fc1b, fc2w, fc2b, (float*)d_out, N);
}

// Round 4
// 989.071 us; speedup vs baseline: 2.7039x; 1.0136x over previous
//
#include <hip/hip_runtime.h>
#include <math.h>

#define DEV __device__ __forceinline__

#define LOG2E 1.4426950408889634f

DEV float fexp(float x)  { return __builtin_amdgcn_exp2f(LOG2E * x); }
DEV float fsigm(float x) { return __builtin_amdgcn_rcpf(1.0f + __builtin_amdgcn_exp2f(-LOG2E * x)); }
DEV float ftanh(float x) { return 1.0f - 2.0f * __builtin_amdgcn_rcpf(__builtin_amdgcn_exp2f(2.0f * LOG2E * x) + 1.0f); }
DEV float lrelu02(float x) { return x > 0.0f ? x : 0.2f * x; }
DEV float readl(float v, int l) {
    return __int_as_float(__builtin_amdgcn_readlane(__float_as_int(v), l));
}
DEV int readli(int v, int l) { return __builtin_amdgcn_readlane(v, l); }

// ---------------------------------------------------------------------------
// Front kernel: block 0 = full 2-layer LSTM recurrence (pipelined, balanced
// 3x256 split, 64 FMAs/thread/step). Blocks [1, 1+degB) = degree histogram.
// Blocks [1+degB, ...) = GAT-1 partial GEMM Wxp = nf @ W1[:16]  (NO tsb bias;
// tsb is folded in later via scalar fixups in k_att / k_msg_csr).
// ---------------------------------------------------------------------------
__global__ __launch_bounds__(768) void k_front(
    const float* __restrict__ ts,
    const float* __restrict__ Wih0, const float* __restrict__ Whh0, const float* __restrict__ b0,
    const float* __restrict__ Wih1, const float* __restrict__ Whh1, const float* __restrict__ b1,
    const float* __restrict__ W1, float* __restrict__ tsb,
    const int* __restrict__ ei, int* __restrict__ deg,
    const float* __restrict__ nf, float* __restrict__ Wxp,
    int N, int E, int T, int degB, int gemB)
{
    __shared__ __align__(16) float h0s[64], h1s[64];
    __shared__ float g0[256], g1a[256], g1b[256];
    __shared__ float tss[1024];
    const int tid = threadIdx.x;

    if (blockIdx.x == 0) {
        // ----- LSTM -----
        const int j = tid & 255;
        const int seg = tid >> 8;          // 0: l0, 1: l1 (Whh1@h1), 2: l1 (Wih1@h0)
        float wv[64], wih0r[3], bias;
        if (seg == 0) {
            bias = b0[j];
            wih0r[0] = Wih0[j*3+0]; wih0r[1] = Wih0[j*3+1]; wih0r[2] = Wih0[j*3+2];
#pragma unroll
            for (int k = 0; k < 64; k++) wv[k] = Whh0[j * 64 + k];
        } else if (seg == 1) {
            bias = b1[j];
            wih0r[0] = wih0r[1] = wih0r[2] = 0.f;
#pragma unroll
            for (int k = 0; k < 64; k++) wv[k] = Whh1[j * 64 + k];
        } else {
            bias = 0.f;
            wih0r[0] = wih0r[1] = wih0r[2] = 0.f;
#pragma unroll
            for (int k = 0; k < 64; k++) wv[k] = Wih1[j * 64 + k];
        }
        for (int i = tid; i < 3 * T && i < 1024; i += 768) tss[i] = ts[i];
        if (tid < 64) { h0s[tid] = 0.f; h1s[tid] = 0.f; }
        float creg = 0.0f;                 // c0 in wave0 lanes, c1 in wave4 lanes
        __syncthreads();

        for (int k = 0; k <= T; ++k) {
            if (seg == 0) {
                if (k < T) {
                    float a0 = bias, a1 = 0.f, a2 = 0.f, a3 = 0.f;
                    a0 = fmaf(tss[3*k+0], wih0r[0], a0);
                    a1 = fmaf(tss[3*k+1], wih0r[1], a1);
                    a2 = fmaf(tss[3*k+2], wih0r[2], a2);
#pragma unroll
                    for (int q = 0; q < 64; q += 16) {
                        float4 u0 = *(const float4*)&h0s[q];
                        float4 u1 = *(const float4*)&h0s[q+4];
                        float4 u2 = *(const float4*)&h0s[q+8];
                        float4 u3 = *(const float4*)&h0s[q+12];
                        a0 = fmaf(u0.x, wv[q+0],  a0); a0 = fmaf(u0.y, wv[q+1],  a0);
                        a0 = fmaf(u0.z, wv[q+2],  a0); a0 = fmaf(u0.w, wv[q+3],  a0);
                        a1 = fmaf(u1.x, wv[q+4],  a1); a1 = fmaf(u1.y, wv[q+5],  a1);
                        a1 = fmaf(u1.z, wv[q+6],  a1); a1 = fmaf(u1.w, wv[q+7],  a1);
                        a2 = fmaf(u2.x, wv[q+8],  a2); a2 = fmaf(u2.y, wv[q+9],  a2);
                        a2 = fmaf(u2.z, wv[q+10], a2); a2 = fmaf(u2.w, wv[q+11], a2);
                        a3 = fmaf(u3.x, wv[q+12], a3); a3 = fmaf(u3.y, wv[q+13], a3);
                        a3 = fmaf(u3.z, wv[q+14], a3); a3 = fmaf(u3.w, wv[q+15], a3);
                    }
                    g0[j] = (a0 + a1) + (a2 + a3);
                }
            } else {
                if (k >= 1) {
                    const float* hsrc = (seg == 1) ? h1s : h0s;
                    float a0 = bias, a1 = 0.f, a2 = 0.f, a3 = 0.f;
#pragma unroll
                    for (int q = 0; q < 64; q += 16) {
                        float4 u0 = *(const float4*)&hsrc[q];
                        float4 u1 = *(const float4*)&hsrc[q+4];
                        float4 u2 = *(const float4*)&hsrc[q+8];
                        float4 u3 = *(const float4*)&hsrc[q+12];
                        a0 = fmaf(u0.x, wv[q+0],  a0); a0 = fmaf(u0.y, wv[q+1],  a0);
                        a0 = fmaf(u0.z, wv[q+2],  a0); a0 = fmaf(u0.w, wv[q+3],  a0);
                        a1 = fmaf(u1.x, wv[q+4],  a1); a1 = fmaf(u1.y, wv[q+5],  a1);
                        a1 = fmaf(u1.z, wv[q+6],  a1); a1 = fmaf(u1.w, wv[q+7],  a1);
                        a2 = fmaf(u2.x, wv[q+8],  a2); a2 = fmaf(u2.y, wv[q+9],  a2);
                        a2 = fmaf(u2.z, wv[q+10], a2); a2 = fmaf(u2.w, wv[q+11], a2);
                        a3 = fmaf(u3.x, wv[q+12], a3); a3 = fmaf(u3.y, wv[q+13], a3);
                        a3 = fmaf(u3.z, wv[q+14], a3); a3 = fmaf(u3.w, wv[q+15], a3);
                    }
                    float r = (a0 + a1) + (a2 + a3);
                    if (seg == 1) g1a[j] = r; else g1b[j] = r;
                }
            }
            __syncthreads();
            if (tid < 64) {
                if (k < T) {
                    float i = fsigm(g0[tid]), f = fsigm(g0[tid+64]);
                    float gg = ftanh(g0[tid+128]), o = fsigm(g0[tid+192]);
                    creg = f * creg + i * gg;
                    h0s[tid] = o * ftanh(creg);
                }
            } else if (tid >= 256 && tid < 320) {
                if (k >= 1) {
                    int l = tid - 256;
                    float i = fsigm(g1a[l]      + g1b[l]);
                    float f = fsigm(g1a[l+64]   + g1b[l+64]);
                    float gg = ftanh(g1a[l+128] + g1b[l+128]);
                    float o = fsigm(g1a[l+192]  + g1b[l+192]);
                    creg = f * creg + i * gg;
                    h1s[l] = o * ftanh(creg);
                }
            }
            __syncthreads();
        }
        // epilogue: tsb[c] = sum_k h1[k] * W1[16+k][c]
        if (tid < 128) {
            float acc = 0.f;
#pragma unroll
            for (int kk = 0; kk < 64; kk++)
                acc = fmaf(h1s[kk], W1[(16 + kk) * 128 + tid], acc);
            tsb[tid] = acc;
        }
    } else if (blockIdx.x <= degB) {
        // ----- degree histogram -----
        int idx = (blockIdx.x - 1) * 768 + tid;
        int stride = degB * 768;
        for (int e = idx; e < E; e += stride)
            atomicAdd(&deg[ei[E + e]], 1);
    } else {
        // ----- GAT-1 partial GEMM: Wxp[n][c] = sum_{k<16} nf[n][k]*W1[k][c] -----
        int lane = tid & 63;
        int bw = (blockIdx.x - 1 - degB) * 12 + (tid >> 6);
        int half = bw & 1;
        int col = lane + 64 * half;
        float wreg[16];
#pragma unroll
        for (int k = 0; k < 16; k++) wreg[k] = W1[k * 128 + col];
        int nstride = (gemB * 12) >> 1;
        for (int n = (bw >> 1); n < N; n += nstride) {
            int nu = __builtin_amdgcn_readfirstlane(n);
            const float* xrow = nf + (size_t)nu * 16;
            float acc = 0.f;
#pragma unroll
            for (int k = 0; k < 16; k++) acc = fmaf(xrow[k], wreg[k], acc);
            Wxp[(size_t)nu * 128 + col] = acc;
        }
    }
}

// ---------------------------------------------------------------------------
// GEMM: Y[n][c] = sum_k X[n][k]*W[k][c], C=128 fixed (layer-2 only now).
// ---------------------------------------------------------------------------
template <int K>
__global__ __launch_bounds__(256) void k_gemm(
    const float* __restrict__ X, const float* __restrict__ W,
    float* __restrict__ Y, int N)
{
    int tid = threadIdx.x;
    int lane = tid & 63;
    int gw = (blockIdx.x * blockDim.x + tid) >> 6;
    int half = gw & 1;
    int col = lane + 64 * half;
    float wreg[K];
#pragma unroll
    for (int k = 0; k < K; k++) wreg[k] = W[k * 128 + col];
    int total_waves = (gridDim.x * blockDim.x) >> 6;
    int nstride = total_waves >> 1;
    for (int n = (gw >> 1); n < N; n += nstride) {
        int nu = __builtin_amdgcn_readfirstlane(n);
        const float* xrow = X + (size_t)nu * K;
        float acc = 0.f;
#pragma unroll
        for (int k = 0; k < K; k++) acc = fmaf(xrow[k], wreg[k], acc);
        Y[(size_t)nu * 128 + col] = acc;
    }
}

// ---------------------------------------------------------------------------
// Attention projections. FIX=1: inputs are Wxp (missing +tsb); add the
// per-head constants cs[h]=tsb@A[:C,h], cd[h]=tsb@A[C:,h] computed in-wave.
// ---------------------------------------------------------------------------
template <int FIX>
__global__ __launch_bounds__(256) void k_att(
    const float* __restrict__ Wx, const float* __restrict__ A,
    const float* __restrict__ tsb,
    float* __restrict__ asrc, float* __restrict__ adst, int N)
{
    int tid = threadIdx.x;
    int lane = tid & 63;
    int gw = (blockIdx.x * blockDim.x + tid) >> 6;
    int waves = (gridDim.x * blockDim.x) >> 6;
    float4 s0 = ((const float4*)A)[lane];
    float4 s1 = ((const float4*)A)[lane + 64];
    float4 d0 = ((const float4*)A)[lane + 128];
    float4 d1 = ((const float4*)A)[lane + 192];
    float cs[4] = {0.f,0.f,0.f,0.f}, cd[4] = {0.f,0.f,0.f,0.f};
    if (FIX) {
        float t0 = tsb[lane], t1 = tsb[64 + lane];
        cs[0] = t0*s0.x + t1*s1.x; cs[1] = t0*s0.y + t1*s1.y;
        cs[2] = t0*s0.z + t1*s1.z; cs[3] = t0*s0.w + t1*s1.w;
        cd[0] = t0*d0.x + t1*d1.x; cd[1] = t0*d0.y + t1*d1.y;
        cd[2] = t0*d0.z + t1*d1.z; cd[3] = t0*d0.w + t1*d1.w;
#pragma unroll
        for (int off = 32; off; off >>= 1) {
#pragma unroll
            for (int h = 0; h < 4; h++) {
                cs[h] += __shfl_xor(cs[h], off, 64);
                cd[h] += __shfl_xor(cd[h], off, 64);
            }
        }
    }
    for (int n = gw; n < N; n += waves) {
        float w0 = Wx[(size_t)n * 128 + lane];
        float w1 = Wx[(size_t)n * 128 + 64 + lane];
        float as[4], ad[4];
        as[0] = w0*s0.x + w1*s1.x; as[1] = w0*s0.y + w1*s1.y;
        as[2] = w0*s0.z + w1*s1.z; as[3] = w0*s0.w + w1*s1.w;
        ad[0] = w0*d0.x + w1*d1.x; ad[1] = w0*d0.y + w1*d1.y;
        ad[2] = w0*d0.z + w1*d1.z; ad[3] = w0*d0.w + w1*d1.w;
#pragma unroll
        for (int off = 32; off; off >>= 1) {
#pragma unroll
            for (int h = 0; h < 4; h++) {
                as[h] += __shfl_xor(as[h], off, 64);
                ad[h] += __shfl_xor(ad[h], off, 64);
            }
        }
        if (lane == 0) {
            float4 o1; o1.x = as[0]+cs[0]; o1.y = as[1]+cs[1];
            o1.z = as[2]+cs[2]; o1.w = as[3]+cs[3];
            float4 o2; o2.x = ad[0]+cd[0]; o2.y = ad[1]+cd[1];
            o2.z = ad[2]+cd[2]; o2.w = ad[3]+cd[3];
            ((float4*)asrc)[n] = o1;
            ((float4*)adst)[n] = o2;
        }
    }
}

// ---------------------------------------------------------------------------
// CSR build: scan of degrees + scatter of src ids.
// ---------------------------------------------------------------------------
__global__ __launch_bounds__(256) void k_scan1(
    const int* __restrict__ deg, int* __restrict__ excl, int* __restrict__ bsum, int N)
{
    int tid = threadIdx.x;
    int base = blockIdx.x * 1024 + tid * 4;
    int d0 = base + 0 < N ? deg[base + 0] : 0;
    int d1 = base + 1 < N ? deg[base + 1] : 0;
    int d2 = base + 2 < N ? deg[base + 2] : 0;
    int d3 = base + 3 < N ? deg[base + 3] : 0;
    int tsum = d0 + d1 + d2 + d3;
    int lane = tid & 63, wid = tid >> 6;
    int incl = tsum;
#pragma unroll
    for (int off = 1; off < 64; off <<= 1) {
        int t = __shfl_up(incl, off, 64);
        if (lane >= off) incl += t;
    }
    __shared__ int wsum[4];
    if (lane == 63) wsum[wid] = incl;
    __syncthreads();
    int woff = 0;
#pragma unroll
    for (int w = 0; w < 4; w++) if (w < wid) woff += wsum[w];
    int tex = woff + incl - tsum;
    if (base + 0 < N) excl[base + 0] = tex;
    if (base + 1 < N) excl[base + 1] = tex + d0;
    if (base + 2 < N) excl[base + 2] = tex + d0 + d1;
    if (base + 3 < N) excl[base + 3] = tex + d0 + d1 + d2;
    if (tid == 255) bsum[blockIdx.x] = woff + incl;
}

__global__ __launch_bounds__(256) void k_scan2(int* __restrict__ bsum, int nb)
{
    __shared__ int tmp[256];
    int tid = threadIdx.x;
    int v = tid < nb ? bsum[tid] : 0;
    tmp[tid] = v;
    __syncthreads();
    for (int off = 1; off < 256; off <<= 1) {
        int t = (tid >= off) ? tmp[tid - off] : 0;
        __syncthreads();
        tmp[tid] += t;
        __syncthreads();
    }
    if (tid < nb) bsum[tid] = tmp[tid] - v;
}

__global__ __launch_bounds__(256) void k_scan3(
    int* __restrict__ excl, const int* __restrict__ bsum,
    int* __restrict__ rowptr, int* __restrict__ fill, int N, int E)
{
    int tid = threadIdx.x;
    int base = blockIdx.x * 1024 + tid * 4;
    int off = bsum[blockIdx.x];
#pragma unroll
    for (int i = 0; i < 4; i++) {
        int idx = base + i;
        if (idx < N) {
            int v = excl[idx] + off;
            rowptr[idx] = v;
            fill[idx] = v;
        }
    }
    if (blockIdx.x == 0 && tid == 0) rowptr[N] = E;
}

__global__ __launch_bounds__(256) void k_scatter(
    const int* __restrict__ ei, int* __restrict__ fill, int* __restrict__ esrc, int E)
{
    int stride = gridDim.x * blockDim.x;
    for (int e = blockIdx.x * blockDim.x + threadIdx.x; e < E; e += stride) {
        int s = ei[e], d = ei[E + e];
        int pos = atomicAdd(&fill[d], 1);
        esrc[pos] = s;
    }
}

// ---------------------------------------------------------------------------
// Fused GAT aggregate, CSR gather form. Wave per dst node. Chunk-0 (deg<=64)
// exp values stay in registers (single asrc gather for ~all nodes).
// LAYER1=1: Wx is Wxp (missing +tsb) -> add csum*tsb, apply /4 + ELU.
//           csum = sum_e coef_e = sum_h den_h/(den_h+eps) (free from denoms).
// ---------------------------------------------------------------------------
template <int LAYER1>
__global__ __launch_bounds__(256) void k_msg_csr(
    const int* __restrict__ rowptr, const int* __restrict__ esrc,
    const float* __restrict__ asrc, const float* __restrict__ adst,
    const float* __restrict__ Wx, const float* __restrict__ tsb,
    float* __restrict__ out, int N)
{
    int tid = threadIdx.x;
    int lane = tid & 63;
    int gw = (blockIdx.x * blockDim.x + tid) >> 6;
    int waves = (gridDim.x * blockDim.x) >> 6;
    float tb0 = 0.f, tb1 = 0.f;
    if (LAYER1) { tb0 = tsb[lane]; tb1 = tsb[64 + lane]; }
    for (int n = gw; n < N; n += waves) {
        int nu = __builtin_amdgcn_readfirstlane(n);
        int beg = rowptr[nu], end = rowptr[nu + 1];
        float4 ad = ((const float4*)adst)[nu];

        // chunk 0: exps into registers
        int e0 = beg + lane;
        bool v0 = e0 < end;
        int s0 = v0 ? esrc[e0] : 0;
        float4 a0 = ((const float4*)asrc)[s0];
        float x0 = v0 ? fexp(lrelu02(a0.x + ad.x)) : 0.f;
        float x1 = v0 ? fexp(lrelu02(a0.y + ad.y)) : 0.f;
        float x2 = v0 ? fexp(lrelu02(a0.z + ad.z)) : 0.f;
        float x3 = v0 ? fexp(lrelu02(a0.w + ad.w)) : 0.f;
        float d0 = x0, d1 = x1, d2 = x2, d3 = x3;
        for (int c = beg + 64; c < end; c += 64) {     // rare (deg > 64)
            int e = c + lane;
            bool v = e < end;
            int s = v ? esrc[e] : 0;
            float4 a = ((const float4*)asrc)[s];
            if (v) {
                d0 += fexp(lrelu02(a.x + ad.x));
                d1 += fexp(lrelu02(a.y + ad.y));
                d2 += fexp(lrelu02(a.z + ad.z));
                d3 += fexp(lrelu02(a.w + ad.w));
            }
        }
#pragma unroll
        for (int off = 32; off; off >>= 1) {
            d0 += __shfl_xor(d0, off, 64);
            d1 += __shfl_xor(d1, off, 64);
            d2 += __shfl_xor(d2, off, 64);
            d3 += __shfl_xor(d3, off, 64);
        }
        float r0 = __builtin_amdgcn_rcpf(d0 + 2e-9f);
        float r1 = __builtin_amdgcn_rcpf(d1 + 2e-9f);
        float r2 = __builtin_amdgcn_rcpf(d2 + 2e-9f);
        float r3 = __builtin_amdgcn_rcpf(d3 + 2e-9f);

        float acc0, acc1;
        if (LAYER1) {
            float csum = d0*r0 + d1*r1 + d2*r2 + d3*r3;
            acc0 = csum * tb0; acc1 = csum * tb1;
        } else {
            acc0 = 0.f; acc1 = 0.f;
        }

        // pass B chunk 0: coef from registers
        float coef = x0*r0 + x1*r1 + x2*r2 + x3*r3;
        int ne = min(64, end - beg);
#pragma unroll 2
        for (int jj = 0; jj < ne; ++jj) {
            int sj = readli(s0, jj);
            float cj = readl(coef, jj);
            const float* wrow = Wx + (size_t)sj * 128;
            acc0 = fmaf(cj, wrow[lane], acc0);
            acc1 = fmaf(cj, wrow[64 + lane], acc1);
        }
        for (int c = beg + 64; c < end; c += 64) {     // rare
            int e = c + lane;
            bool v = e < end;
            int s = v ? esrc[e] : 0;
            float4 a = ((const float4*)asrc)[s];
            float cf = 0.f;
            if (v) {
                cf = fexp(lrelu02(a.x + ad.x)) * r0
                   + fexp(lrelu02(a.y + ad.y)) * r1
                   + fexp(lrelu02(a.z + ad.z)) * r2
                   + fexp(lrelu02(a.w + ad.w)) * r3;
            }
            int nee = min(64, end - c);
#pragma unroll 2
            for (int jj = 0; jj < nee; ++jj) {
                int sj = readli(s, jj);
                float cj = readl(cf, jj);
                const float* wrow = Wx + (size_t)sj * 128;
                acc0 = fmaf(cj, wrow[lane], acc0);
                acc1 = fmaf(cj, wrow[64 + lane], acc1);
            }
        }
        if (LAYER1) {
            acc0 *= 0.25f; acc1 *= 0.25f;
            acc0 = acc0 > 0.f ? acc0 : expm1f(acc0);
            acc1 = acc1 > 0.f ? acc1 : expm1f(acc1);
        }
        out[(size_t)nu * 128 + lane] = acc0;
        out[(size_t)nu * 128 + 64 + lane] = acc1;
    }
}

// ---------------------------------------------------------------------------
// Fused ELU + FC head. Wave per node.
// ---------------------------------------------------------------------------
__global__ __launch_bounds__(256) void k_fc(
    const float* __restrict__ acc2, const float* __restrict__ fc1w,
    const float* __restrict__ fc1b, const float* __restrict__ fc2w,
    const float* __restrict__ fc2b, float* __restrict__ out, int N)
{
    int tid = threadIdx.x;
    int lane = tid & 63;
    int gw = (blockIdx.x * blockDim.x + tid) >> 6;
    int waves = (gridDim.x * blockDim.x) >> 6;
    float w1reg[128];
#pragma unroll
    for (int c = 0; c < 128; c++) w1reg[c] = fc1w[c * 64 + lane];
    float b1v = fc1b[lane];
    float w2 = fc2w[lane];
    float b2 = fc2b[0];
    for (int n = gw; n < N; n += waves) {
        float x0 = acc2[(size_t)n * 128 + lane] * 0.25f;
        float x1 = acc2[(size_t)n * 128 + 64 + lane] * 0.25f;
        x0 = x0 > 0.f ? x0 : expm1f(x0);
        x1 = x1 > 0.f ? x1 : expm1f(x1);
        float h = b1v;
#pragma unroll
        for (int c = 0; c < 64; c++) h += readl(x0, c) * w1reg[c];
#pragma unroll
        for (int c = 0; c < 64; c++) h += readl(x1, c) * w1reg[64 + c];
        float r = fmaxf(h, 0.0f) * w2;
#pragma unroll
        for (int off = 32; off; off >>= 1) r += __shfl_xor(r, off, 64);
        if (lane == 0) out[n] = r + b2;
    }
}

extern "C" void kernel_launch(void* const* d_in, const int* in_sizes, int n_in,
                              void* d_out, int out_size, void* d_ws, size_t ws_size,
                              hipStream_t stream)
{
    const float* nf   = (const float*)d_in[0];
    const int*   ei   = (const int*)  d_in[1];
    const float* ts   = (const float*)d_in[2];
    const float* Wih0 = (const float*)d_in[3];
    const float* Whh0 = (const float*)d_in[4];
    const float* b0   = (const float*)d_in[5];
    const float* Wih1 = (const float*)d_in[6];
    const float* Whh1 = (const float*)d_in[7];
    const float* b1   = (const float*)d_in[8];
    const float* W1   = (const float*)d_in[9];
    const float* A1   = (const float*)d_in[10];
    const float* W2   = (const float*)d_in[11];
    const float* A2   = (const float*)d_in[12];
    const float* fc1w = (const float*)d_in[13];
    const float* fc1b = (const float*)d_in[14];
    const float* fc2w = (const float*)d_in[15];
    const float* fc2b = (const float*)d_in[16];

    int N = in_sizes[0] / 16;
    int E = in_sizes[1] / 2;
    int T = in_sizes[2] / 3;

    char* ws = (char*)d_ws;
    size_t off = 0;
    auto alloc = [&](size_t bytes) {
        char* p = ws + off;
        off = (off + bytes + 255) & ~(size_t)255;
        return p;
    };
    float* tsb    = (float*)alloc(512);
    float* asrc   = (float*)alloc((size_t)N * 4 * sizeof(float));
    float* adst   = (float*)alloc((size_t)N * 4 * sizeof(float));
    int*   rowptr = (int*)  alloc((size_t)(N + 1) * sizeof(int));
    int*   esrc   = (int*)  alloc((size_t)E * sizeof(int));
    int*   degfil = (int*)  alloc((size_t)N * sizeof(int));
    int*   bsum   = (int*)  alloc(256 * sizeof(int));
    float* bufA   = (float*)alloc((size_t)N * 128 * sizeof(float));
    float* bufB   = (float*)alloc((size_t)N * 128 * sizeof(float));

    int nb_scan = (N + 1023) / 1024;
    const int degB = 64, gemB = 512;

    // ---- front: LSTM (block 0) || degree histogram || GAT-1 partial GEMM ----
    hipMemsetAsync(degfil, 0, (size_t)N * sizeof(int), stream);
    k_front<<<1 + degB + gemB, 768, 0, stream>>>(
        ts, Wih0, Whh0, b0, Wih1, Whh1, b1, W1, tsb,
        ei, degfil, nf, bufA, N, E, T, degB, gemB);

    // ---- CSR (scan + scatter) ----
    k_scan1<<<nb_scan, 256, 0, stream>>>(degfil, rowptr, bsum, N);
    k_scan2<<<1, 256, 0, stream>>>(bsum, nb_scan);
    k_scan3<<<nb_scan, 256, 0, stream>>>(rowptr, bsum, rowptr, degfil, N, E);
    k_scatter<<<2048, 256, 0, stream>>>(ei, degfil, esrc, E);

    // ---- GAT layer 1 (tsb folded in via fixups) ----
    k_att<1><<<1024, 256, 0, stream>>>(bufA, A1, tsb, asrc, adst, N);
    k_msg_csr<1><<<4096, 256, 0, stream>>>(rowptr, esrc, asrc, adst, bufA, tsb, bufB, N);

    // ---- GAT layer 2 ----
    k_gemm<128><<<1024, 256, 0, stream>>>(bufB, W2, bufA, N);
    k_att<0><<<1024, 256, 0, stream>>>(bufA, A2, tsb, asrc, adst, N);
    k_msg_csr<0><<<4096, 256, 0, stream>>>(rowptr, esrc, asrc, adst, bufA, tsb, bufB, N);

    // ---- FC head (fused ELU) ----
    k_fc<<<1024, 256, 0, stream>>>(bufB, fc1w, fc1b, fc2w, fc2b, (float*)d_out, N);
}

// Round 5
// 982.657 us; speedup vs baseline: 2.7215x; 1.0065x over previous
//
#include <hip/hip_runtime.h>
#include <math.h>

#define DEV __device__ __forceinline__

#define LOG2E 1.4426950408889634f

DEV float fexp(float x)  { return __builtin_amdgcn_exp2f(LOG2E * x); }
DEV float fsigm(float x) { return __builtin_amdgcn_rcpf(1.0f + __builtin_amdgcn_exp2f(-LOG2E * x)); }
DEV float ftanh(float x) { return 1.0f - 2.0f * __builtin_amdgcn_rcpf(__builtin_amdgcn_exp2f(2.0f * LOG2E * x) + 1.0f); }
DEV float lrelu02(float x) { return x > 0.0f ? x : 0.2f * x; }
DEV float readl(float v, int l) {
    return __int_as_float(__builtin_amdgcn_readlane(__float_as_int(v), l));
}
DEV int readli(int v, int l) { return __builtin_amdgcn_readlane(v, l); }

// ---------------------------------------------------------------------------
// Front kernel, 512 threads/block, 256 blocks total (~1 block/CU):
//   block 0            : 2-layer LSTM, quad-gate layout, ONE barrier/step.
//   blocks [1, 1+HB)   : degree histogram.
//   blocks [1+HB, 256) : GAT-1 partial GEMM Wxp = nf @ W1[:16] (no tsb bias).
//
// LSTM layout: thread = (seg, u, q): seg = tid>>8 (0: layer0, 1: layer1),
// u = (tid&255)>>2 (hidden unit), q = tid&3 (gate i/f/g/o). The 4 gate
// threads of a unit sit in one lane-quad -> gate exchange via 4 __shfl,
// activation computed redundantly per lane, c-state lives in a register.
// h ping-pong buffers (h0b/h1b[2][64]) -> single __syncthreads per step.
// Layer 1 runs one step behind layer 0.
// ---------------------------------------------------------------------------
__global__ __launch_bounds__(512) void k_front(
    const float* __restrict__ ts,
    const float* __restrict__ Wih0, const float* __restrict__ Whh0, const float* __restrict__ b0,
    const float* __restrict__ Wih1, const float* __restrict__ Whh1, const float* __restrict__ b1,
    const float* __restrict__ W1, float* __restrict__ tsb,
    const int* __restrict__ ei, int* __restrict__ deg,
    const float* __restrict__ nf, float* __restrict__ Wxp,
    int N, int E, int T, int HB, int GB)
{
    __shared__ __align__(16) float h0b[2][64], h1b[2][64];
    __shared__ float tss[512];
    const int tid = threadIdx.x;

    if (blockIdx.x == 0) {
        const int seg = tid >> 8;
        const int idx = tid & 255;
        const int u = idx >> 2;        // hidden unit
        const int q = idx & 3;         // gate (i,f,g,o)
        const int row = q * 64 + u;    // torch gate-row index
        const int lane = tid & 63;
        const int qbase = lane & ~3;

        float wa[64], wb[64], wih[3], bias;
        if (seg == 0) {
            bias = b0[row];
            wih[0] = Wih0[row*3+0]; wih[1] = Wih0[row*3+1]; wih[2] = Wih0[row*3+2];
#pragma unroll
            for (int k = 0; k < 64; k++) wa[k] = Whh0[row * 64 + k];
#pragma unroll
            for (int k = 0; k < 64; k++) wb[k] = 0.0f;
        } else {
            bias = b1[row];
            wih[0] = wih[1] = wih[2] = 0.f;
#pragma unroll
            for (int k = 0; k < 64; k++) wa[k] = Whh1[row * 64 + k];
#pragma unroll
            for (int k = 0; k < 64; k++) wb[k] = Wih1[row * 64 + k];
        }
        for (int i = tid; i < 3 * T && i < 512; i += 512) tss[i] = ts[i];
        if (tid < 64) {
            h0b[0][tid] = 0.f; h0b[1][tid] = 0.f;
            h1b[0][tid] = 0.f; h1b[1][tid] = 0.f;
        }
        float creg = 0.0f;             // c(u) held redundantly by the quad
        __syncthreads();

        for (int k = 0; k <= T; ++k) {
            if (seg == 0) {
                if (k < T) {
                    const float* hprev = h0b[(k + 1) & 1];   // h0(k-1)
                    float a0 = bias, a1 = 0.f, a2 = 0.f, a3 = 0.f;
                    a0 = fmaf(tss[3*k+0], wih[0], a0);
                    a1 = fmaf(tss[3*k+1], wih[1], a1);
                    a2 = fmaf(tss[3*k+2], wih[2], a2);
#pragma unroll
                    for (int p = 0; p < 64; p += 16) {
                        float4 u0 = *(const float4*)&hprev[p];
                        float4 u1 = *(const float4*)&hprev[p+4];
                        float4 u2 = *(const float4*)&hprev[p+8];
                        float4 u3 = *(const float4*)&hprev[p+12];
                        a0 = fmaf(u0.x, wa[p+0],  a0); a0 = fmaf(u0.y, wa[p+1],  a0);
                        a0 = fmaf(u0.z, wa[p+2],  a0); a0 = fmaf(u0.w, wa[p+3],  a0);
                        a1 = fmaf(u1.x, wa[p+4],  a1); a1 = fmaf(u1.y, wa[p+5],  a1);
                        a1 = fmaf(u1.z, wa[p+6],  a1); a1 = fmaf(u1.w, wa[p+7],  a1);
                        a2 = fmaf(u2.x, wa[p+8],  a2); a2 = fmaf(u2.y, wa[p+9],  a2);
                        a2 = fmaf(u2.z, wa[p+10], a2); a2 = fmaf(u2.w, wa[p+11], a2);
                        a3 = fmaf(u3.x, wa[p+12], a3); a3 = fmaf(u3.y, wa[p+13], a3);
                        a3 = fmaf(u3.z, wa[p+14], a3); a3 = fmaf(u3.w, wa[p+15], a3);
                    }
                    float mine = (a0 + a1) + (a2 + a3);
                    float gi = __shfl(mine, qbase + 0, 64);
                    float gf = __shfl(mine, qbase + 1, 64);
                    float gg = __shfl(mine, qbase + 2, 64);
                    float go = __shfl(mine, qbase + 3, 64);
                    creg = fsigm(gf) * creg + fsigm(gi) * ftanh(gg);
                    float h = fsigm(go) * ftanh(creg);
                    if (q == 0) h0b[k & 1][u] = h;
                }
            } else {
                if (k >= 1) {
                    const float* h1prev = h1b[k & 1];        // h1(k-2)
                    const float* h0in   = h0b[(k + 1) & 1];  // h0(k-1)
                    float a0 = bias, a1 = 0.f, a2 = 0.f, a3 = 0.f;
#pragma unroll
                    for (int p = 0; p < 64; p += 8) {
                        float4 u0 = *(const float4*)&h1prev[p];
                        float4 u1 = *(const float4*)&h1prev[p+4];
                        a0 = fmaf(u0.x, wa[p+0], a0); a0 = fmaf(u0.y, wa[p+1], a0);
                        a0 = fmaf(u0.z, wa[p+2], a0); a0 = fmaf(u0.w, wa[p+3], a0);
                        a1 = fmaf(u1.x, wa[p+4], a1); a1 = fmaf(u1.y, wa[p+5], a1);
                        a1 = fmaf(u1.z, wa[p+6], a1); a1 = fmaf(u1.w, wa[p+7], a1);
                        float4 v0 = *(const float4*)&h0in[p];
                        float4 v1 = *(const float4*)&h0in[p+4];
                        a2 = fmaf(v0.x, wb[p+0], a2); a2 = fmaf(v0.y, wb[p+1], a2);
                        a2 = fmaf(v0.z, wb[p+2], a2); a2 = fmaf(v0.w, wb[p+3], a2);
                        a3 = fmaf(v1.x, wb[p+4], a3); a3 = fmaf(v1.y, wb[p+5], a3);
                        a3 = fmaf(v1.z, wb[p+6], a3); a3 = fmaf(v1.w, wb[p+7], a3);
                    }
                    float mine = (a0 + a1) + (a2 + a3);
                    float gi = __shfl(mine, qbase + 0, 64);
                    float gf = __shfl(mine, qbase + 1, 64);
                    float gg = __shfl(mine, qbase + 2, 64);
                    float go = __shfl(mine, qbase + 3, 64);
                    creg = fsigm(gf) * creg + fsigm(gi) * ftanh(gg);
                    float h = fsigm(go) * ftanh(creg);
                    if (q == 0) h1b[(k + 1) & 1][u] = h;     // h1(k-1)
                }
            }
            __syncthreads();
        }
        // epilogue: tsb[c] = sum_k h1[k] * W1[16+k][c];  final h1 = h1(T-1)
        if (tid < 128) {
            const float* hf = h1b[(T - 1) & 1];
            float acc = 0.f;
#pragma unroll
            for (int kk = 0; kk < 64; kk++)
                acc = fmaf(hf[kk], W1[(16 + kk) * 128 + tid], acc);
            tsb[tid] = acc;
        }
    } else if (blockIdx.x <= HB) {
        // ----- degree histogram -----
        int idx = (blockIdx.x - 1) * 512 + tid;
        int stride = HB * 512;
        for (int e = idx; e < E; e += stride)
            atomicAdd(&deg[ei[E + e]], 1);
    } else {
        // ----- GAT-1 partial GEMM: Wxp[n][c] = sum_{k<16} nf[n][k]*W1[k][c] -----
        int lane = tid & 63;
        int bw = (blockIdx.x - 1 - HB) * 8 + (tid >> 6);
        int half = bw & 1;
        int col = lane + 64 * half;
        float wreg[16];
#pragma unroll
        for (int k = 0; k < 16; k++) wreg[k] = W1[k * 128 + col];
        int nstride = (GB * 8) >> 1;
        for (int n = (bw >> 1); n < N; n += nstride) {
            int nu = __builtin_amdgcn_readfirstlane(n);
            const float* xrow = nf + (size_t)nu * 16;
            float acc = 0.f;
#pragma unroll
            for (int k = 0; k < 16; k++) acc = fmaf(xrow[k], wreg[k], acc);
            Wxp[(size_t)nu * 128 + col] = acc;
        }
    }
}

// ---------------------------------------------------------------------------
// GEMM: Y[n][c] = sum_k X[n][k]*W[k][c], C=128 fixed (layer-2 only).
// ---------------------------------------------------------------------------
template <int K>
__global__ __launch_bounds__(256) void k_gemm(
    const float* __restrict__ X, const float* __restrict__ W,
    float* __restrict__ Y, int N)
{
    int tid = threadIdx.x;
    int lane = tid & 63;
    int gw = (blockIdx.x * blockDim.x + tid) >> 6;
    int half = gw & 1;
    int col = lane + 64 * half;
    float wreg[K];
#pragma unroll
    for (int k = 0; k < K; k++) wreg[k] = W[k * 128 + col];
    int total_waves = (gridDim.x * blockDim.x) >> 6;
    int nstride = total_waves >> 1;
    for (int n = (gw >> 1); n < N; n += nstride) {
        int nu = __builtin_amdgcn_readfirstlane(n);
        const float* xrow = X + (size_t)nu * K;
        float acc = 0.f;
#pragma unroll
        for (int k = 0; k < K; k++) acc = fmaf(xrow[k], wreg[k], acc);
        Y[(size_t)nu * 128 + col] = acc;
    }
}

// ---------------------------------------------------------------------------
// Attention projections; lane owns column pair (2l, 2l+1).
// FIX=1: inputs are Wxp (missing +tsb); add per-head constants from tsb.
// ---------------------------------------------------------------------------
template <int FIX>
__global__ __launch_bounds__(256) void k_att(
    const float* __restrict__ Wx, const float* __restrict__ A,
    const float* __restrict__ tsb,
    float* __restrict__ asrc, float* __restrict__ adst, int N)
{
    int tid = threadIdx.x;
    int lane = tid & 63;
    int gw = (blockIdx.x * blockDim.x + tid) >> 6;
    int waves = (gridDim.x * blockDim.x) >> 6;
    float4 s0 = ((const float4*)A)[2*lane];        // A row 2l  (src half)
    float4 s1 = ((const float4*)A)[2*lane + 1];    // A row 2l+1
    float4 d0 = ((const float4*)A)[128 + 2*lane];  // dst half
    float4 d1 = ((const float4*)A)[128 + 2*lane + 1];
    float cs[4] = {0.f,0.f,0.f,0.f}, cd[4] = {0.f,0.f,0.f,0.f};
    if (FIX) {
        float2 t = ((const float2*)tsb)[lane];
        cs[0] = t.x*s0.x + t.y*s1.x; cs[1] = t.x*s0.y + t.y*s1.y;
        cs[2] = t.x*s0.z + t.y*s1.z; cs[3] = t.x*s0.w + t.y*s1.w;
        cd[0] = t.x*d0.x + t.y*d1.x; cd[1] = t.x*d0.y + t.y*d1.y;
        cd[2] = t.x*d0.z + t.y*d1.z; cd[3] = t.x*d0.w + t.y*d1.w;
#pragma unroll
        for (int off = 32; off; off >>= 1) {
#pragma unroll
            for (int h = 0; h < 4; h++) {
                cs[h] += __shfl_xor(cs[h], off, 64);
                cd[h] += __shfl_xor(cd[h], off, 64);
            }
        }
    }
    for (int n = gw; n < N; n += waves) {
        float2 w = ((const float2*)(Wx + (size_t)n * 128))[lane];
        float as[4], ad[4];
        as[0] = w.x*s0.x + w.y*s1.x; as[1] = w.x*s0.y + w.y*s1.y;
        as[2] = w.x*s0.z + w.y*s1.z; as[3] = w.x*s0.w + w.y*s1.w;
        ad[0] = w.x*d0.x + w.y*d1.x; ad[1] = w.x*d0.y + w.y*d1.y;
        ad[2] = w.x*d0.z + w.y*d1.z; ad[3] = w.x*d0.w + w.y*d1.w;
#pragma unroll
        for (int off = 32; off; off >>= 1) {
#pragma unroll
            for (int h = 0; h < 4; h++) {
                as[h] += __shfl_xor(as[h], off, 64);
                ad[h] += __shfl_xor(ad[h], off, 64);
            }
        }
        if (lane == 0) {
            float4 o1; o1.x = as[0]+cs[0]; o1.y = as[1]+cs[1];
            o1.z = as[2]+cs[2]; o1.w = as[3]+cs[3];
            float4 o2; o2.x = ad[0]+cd[0]; o2.y = ad[1]+cd[1];
            o2.z = ad[2]+cd[2]; o2.w = ad[3]+cd[3];
            ((float4*)asrc)[n] = o1;
            ((float4*)adst)[n] = o2;
        }
    }
}

// ---------------------------------------------------------------------------
// CSR build: scan of degrees + scatter of src ids.
// ---------------------------------------------------------------------------
__global__ __launch_bounds__(256) void k_scan1(
    const int* __restrict__ deg, int* __restrict__ excl, int* __restrict__ bsum, int N)
{
    int tid = threadIdx.x;
    int base = blockIdx.x * 1024 + tid * 4;
    int d0 = base + 0 < N ? deg[base + 0] : 0;
    int d1 = base + 1 < N ? deg[base + 1] : 0;
    int d2 = base + 2 < N ? deg[base + 2] : 0;
    int d3 = base + 3 < N ? deg[base + 3] : 0;
    int tsum = d0 + d1 + d2 + d3;
    int lane = tid & 63, wid = tid >> 6;
    int incl = tsum;
#pragma unroll
    for (int off = 1; off < 64; off <<= 1) {
        int t = __shfl_up(incl, off, 64);
        if (lane >= off) incl += t;
    }
    __shared__ int wsum[4];
    if (lane == 63) wsum[wid] = incl;
    __syncthreads();
    int woff = 0;
#pragma unroll
    for (int w = 0; w < 4; w++) if (w < wid) woff += wsum[w];
    int tex = woff + incl - tsum;
    if (base + 0 < N) excl[base + 0] = tex;
    if (base + 1 < N) excl[base + 1] = tex + d0;
    if (base + 2 < N) excl[base + 2] = tex + d0 + d1;
    if (base + 3 < N) excl[base + 3] = tex + d0 + d1 + d2;
    if (tid == 255) bsum[blockIdx.x] = woff + incl;
}

__global__ __launch_bounds__(256) void k_scan2(int* __restrict__ bsum, int nb)
{
    __shared__ int tmp[256];
    int tid = threadIdx.x;
    int v = tid < nb ? bsum[tid] : 0;
    tmp[tid] = v;
    __syncthreads();
    for (int off = 1; off < 256; off <<= 1) {
        int t = (tid >= off) ? tmp[tid - off] : 0;
        __syncthreads();
        tmp[tid] += t;
        __syncthreads();
    }
    if (tid < nb) bsum[tid] = tmp[tid] - v;
}

__global__ __launch_bounds__(256) void k_scan3(
    int* __restrict__ excl, const int* __restrict__ bsum,
    int* __restrict__ rowptr, int* __restrict__ fill, int N, int E)
{
    int tid = threadIdx.x;
    int base = blockIdx.x * 1024 + tid * 4;
    int off = bsum[blockIdx.x];
#pragma unroll
    for (int i = 0; i < 4; i++) {
        int idx = base + i;
        if (idx < N) {
            int v = excl[idx] + off;
            rowptr[idx] = v;
            fill[idx] = v;
        }
    }
    if (blockIdx.x == 0 && tid == 0) rowptr[N] = E;
}

__global__ __launch_bounds__(256) void k_scatter(
    const int* __restrict__ ei, int* __restrict__ fill, int* __restrict__ esrc, int E)
{
    int stride = gridDim.x * blockDim.x;
    for (int e = blockIdx.x * blockDim.x + threadIdx.x; e < E; e += stride) {
        int s = ei[e], d = ei[E + e];
        int pos = atomicAdd(&fill[d], 1);
        esrc[pos] = s;
    }
}

// ---------------------------------------------------------------------------
// Fused GAT aggregate, CSR gather form. Wave per dst node. Chunk-0 (deg<=64)
// exps stay in registers. Lane owns column pair (2l, 2l+1): one float2 load
// per gathered row per lane.
// LAYER1=1: Wx is Wxp (missing +tsb) -> add csum*tsb, apply /4 + ELU.
// ---------------------------------------------------------------------------
template <int LAYER1>
__global__ __launch_bounds__(256) void k_msg_csr(
    const int* __restrict__ rowptr, const int* __restrict__ esrc,
    const float* __restrict__ asrc, const float* __restrict__ adst,
    const float* __restrict__ Wx, const float* __restrict__ tsb,
    float* __restrict__ out, int N)
{
    int tid = threadIdx.x;
    int lane = tid & 63;
    int gw = (blockIdx.x * blockDim.x + tid) >> 6;
    int waves = (gridDim.x * blockDim.x) >> 6;
    float2 tbv = {0.f, 0.f};
    if (LAYER1) tbv = ((const float2*)tsb)[lane];
    for (int n = gw; n < N; n += waves) {
        int nu = __builtin_amdgcn_readfirstlane(n);
        int beg = rowptr[nu], end = rowptr[nu + 1];
        float4 ad = ((const float4*)adst)[nu];

        // chunk 0: exps into registers
        int e0 = beg + lane;
        bool v0 = e0 < end;
        int s0 = v0 ? esrc[e0] : 0;
        float4 a0 = ((const float4*)asrc)[s0];
        float x0 = v0 ? fexp(lrelu02(a0.x + ad.x)) : 0.f;
        float x1 = v0 ? fexp(lrelu02(a0.y + ad.y)) : 0.f;
        float x2 = v0 ? fexp(lrelu02(a0.z + ad.z)) : 0.f;
        float x3 = v0 ? fexp(lrelu02(a0.w + ad.w)) : 0.f;
        float d0 = x0, d1 = x1, d2 = x2, d3 = x3;
        for (int c = beg + 64; c < end; c += 64) {     // rare (deg > 64)
            int e = c + lane;
            bool v = e < end;
            int s = v ? esrc[e] : 0;
            float4 a = ((const float4*)asrc)[s];
            if (v) {
                d0 += fexp(lrelu02(a.x + ad.x));
                d1 += fexp(lrelu02(a.y + ad.y));
                d2 += fexp(lrelu02(a.z + ad.z));
                d3 += fexp(lrelu02(a.w + ad.w));
            }
        }
#pragma unroll
        for (int off = 32; off; off >>= 1) {
            d0 += __shfl_xor(d0, off, 64);
            d1 += __shfl_xor(d1, off, 64);
            d2 += __shfl_xor(d2, off, 64);
            d3 += __shfl_xor(d3, off, 64);
        }
        float r0 = __builtin_amdgcn_rcpf(d0 + 2e-9f);
        float r1 = __builtin_amdgcn_rcpf(d1 + 2e-9f);
        float r2 = __builtin_amdgcn_rcpf(d2 + 2e-9f);
        float r3 = __builtin_amdgcn_rcpf(d3 + 2e-9f);

        float acc0, acc1;
        if (LAYER1) {
            float csum = d0*r0 + d1*r1 + d2*r2 + d3*r3;
            acc0 = csum * tbv.x; acc1 = csum * tbv.y;
        } else {
            acc0 = 0.f; acc1 = 0.f;
        }

        // pass B chunk 0: coef from registers
        float coef = x0*r0 + x1*r1 + x2*r2 + x3*r3;
        int ne = min(64, end - beg);
#pragma unroll 2
        for (int jj = 0; jj < ne; ++jj) {
            int sj = readli(s0, jj);
            float cj = readl(coef, jj);
            float2 wv = ((const float2*)(Wx + (size_t)sj * 128))[lane];
            acc0 = fmaf(cj, wv.x, acc0);
            acc1 = fmaf(cj, wv.y, acc1);
        }
        for (int c = beg + 64; c < end; c += 64) {     // rare
            int e = c + lane;
            bool v = e < end;
            int s = v ? esrc[e] : 0;
            float4 a = ((const float4*)asrc)[s];
            float cf = 0.f;
            if (v) {
                cf = fexp(lrelu02(a.x + ad.x)) * r0
                   + fexp(lrelu02(a.y + ad.y)) * r1
                   + fexp(lrelu02(a.z + ad.z)) * r2
                   + fexp(lrelu02(a.w + ad.w)) * r3;
            }
            int nee = min(64, end - c);
#pragma unroll 2
            for (int jj = 0; jj < nee; ++jj) {
                int sj = readli(s, jj);
                float cj = readl(cf, jj);
                float2 wv = ((const float2*)(Wx + (size_t)sj * 128))[lane];
                acc0 = fmaf(cj, wv.x, acc0);
                acc1 = fmaf(cj, wv.y, acc1);
            }
        }
        if (LAYER1) {
            acc0 *= 0.25f; acc1 *= 0.25f;
            acc0 = acc0 > 0.f ? acc0 : expm1f(acc0);
            acc1 = acc1 > 0.f ? acc1 : expm1f(acc1);
        }
        float2 o; o.x = acc0; o.y = acc1;
        ((float2*)(out + (size_t)nu * 128))[lane] = o;
    }
}

// ---------------------------------------------------------------------------
// Fused ELU + FC head. Wave per node; lane owns column pair (2l, 2l+1).
// ---------------------------------------------------------------------------
__global__ __launch_bounds__(256) void k_fc(
    const float* __restrict__ acc2, const float* __restrict__ fc1w,
    const float* __restrict__ fc1b, const float* __restrict__ fc2w,
    const float* __restrict__ fc2b, float* __restrict__ out, int N)
{
    int tid = threadIdx.x;
    int lane = tid & 63;
    int gw = (blockIdx.x * blockDim.x + tid) >> 6;
    int waves = (gridDim.x * blockDim.x) >> 6;
    float w1reg[128];
#pragma unroll
    for (int c = 0; c < 128; c++) w1reg[c] = fc1w[c * 64 + lane];
    float b1v = fc1b[lane];
    float w2 = fc2w[lane];
    float b2 = fc2b[0];
    for (int n = gw; n < N; n += waves) {
        float2 xv = ((const float2*)(acc2 + (size_t)n * 128))[lane];
        float x0 = xv.x * 0.25f, x1 = xv.y * 0.25f;
        x0 = x0 > 0.f ? x0 : expm1f(x0);
        x1 = x1 > 0.f ? x1 : expm1f(x1);
        float h = b1v;
#pragma unroll
        for (int j = 0; j < 64; j++) {
            h = fmaf(readl(x0, j), w1reg[2*j],     h);
            h = fmaf(readl(x1, j), w1reg[2*j + 1], h);
        }
        float r = fmaxf(h, 0.0f) * w2;
#pragma unroll
        for (int off = 32; off; off >>= 1) r += __shfl_xor(r, off, 64);
        if (lane == 0) out[n] = r + b2;
    }
}

extern "C" void kernel_launch(void* const* d_in, const int* in_sizes, int n_in,
                              void* d_out, int out_size, void* d_ws, size_t ws_size,
                              hipStream_t stream)
{
    const float* nf   = (const float*)d_in[0];
    const int*   ei   = (const int*)  d_in[1];
    const float* ts   = (const float*)d_in[2];
    const float* Wih0 = (const float*)d_in[3];
    const float* Whh0 = (const float*)d_in[4];
    const float* b0   = (const float*)d_in[5];
    const float* Wih1 = (const float*)d_in[6];
    const float* Whh1 = (const float*)d_in[7];
    const float* b1   = (const float*)d_in[8];
    const float* W1   = (const float*)d_in[9];
    const float* A1   = (const float*)d_in[10];
    const float* W2   = (const float*)d_in[11];
    const float* A2   = (const float*)d_in[12];
    const float* fc1w = (const float*)d_in[13];
    const float* fc1b = (const float*)d_in[14];
    const float* fc2w = (const float*)d_in[15];
    const float* fc2b = (const float*)d_in[16];

    int N = in_sizes[0] / 16;
    int E = in_sizes[1] / 2;
    int T = in_sizes[2] / 3;

    char* ws = (char*)d_ws;
    size_t off = 0;
    auto alloc = [&](size_t bytes) {
        char* p = ws + off;
        off = (off + bytes + 255) & ~(size_t)255;
        return p;
    };
    float* tsb    = (float*)alloc(512);
    float* asrc   = (float*)alloc((size_t)N * 4 * sizeof(float));
    float* adst   = (float*)alloc((size_t)N * 4 * sizeof(float));
    int*   rowptr = (int*)  alloc((size_t)(N + 1) * sizeof(int));
    int*   esrc   = (int*)  alloc((size_t)E * sizeof(int));
    int*   degfil = (int*)  alloc((size_t)N * sizeof(int));
    int*   bsum   = (int*)  alloc(256 * sizeof(int));
    float* bufA   = (float*)alloc((size_t)N * 128 * sizeof(float));
    float* bufB   = (float*)alloc((size_t)N * 128 * sizeof(float));

    int nb_scan = (N + 1023) / 1024;
    const int HB = 95, GB = 160;   // 1 + 95 + 160 = 256 blocks

    // ---- front: LSTM (block 0) || degree histogram || GAT-1 partial GEMM ----
    hipMemsetAsync(degfil, 0, (size_t)N * sizeof(int), stream);
    k_front<<<1 + HB + GB, 512, 0, stream>>>(
        ts, Wih0, Whh0, b0, Wih1, Whh1, b1, W1, tsb,
        ei, degfil, nf, bufA, N, E, T, HB, GB);

    // ---- CSR (scan + scatter) ----
    k_scan1<<<nb_scan, 256, 0, stream>>>(degfil, rowptr, bsum, N);
    k_scan2<<<1, 256, 0, stream>>>(bsum, nb_scan);
    k_scan3<<<nb_scan, 256, 0, stream>>>(rowptr, bsum, rowptr, degfil, N, E);
    k_scatter<<<2048, 256, 0, stream>>>(ei, degfil, esrc, E);

    // ---- GAT layer 1 (tsb folded in via fixups) ----
    k_att<1><<<1024, 256, 0, stream>>>(bufA, A1, tsb, asrc, adst, N);
    k_msg_csr<1><<<4096, 256, 0, stream>>>(rowptr, esrc, asrc, adst, bufA, tsb, bufB, N);

    // ---- GAT layer 2 ----
    k_gemm<128><<<1024, 256, 0, stream>>>(bufB, W2, bufA, N);
    k_att<0><<<1024, 256, 0, stream>>>(bufA, A2, tsb, asrc, adst, N);
    k_msg_csr<0><<<4096, 256, 0, stream>>>(rowptr, esrc, asrc, adst, bufA, tsb, bufB, N);

    // ---- FC head (fused ELU) ----
    k_fc<<<1024, 256, 0, stream>>>(bufB, fc1w, fc1b, fc2w, fc2b, (float*)d_out, N);
}